// Round 1
// baseline (2833.365 us; speedup 1.0000x reference)
//
#include <hip/hip_runtime.h>
#include <math.h>

// Shapes: B=8, C=256, H=W=64, HQ=WQ=32, L=1024, NH=8, hd=8, dv=32
// All fp32. Workspace layout (floats):
//   Qp [8*8*1024*8]   = 524288
//   Kp                 = 524288
//   Vp [8*8*1024*32]  = 2097152
//   op_attn [8,256,32,32] = 2097152
//   op_conv [8,256,32,32] = 2097152
//   attn_c  [8,8,256,256] = 4194304
//   fused   [8,512,64,64] = 16777216
// total = 28,311,552 floats ~= 108 MB

// ---------------- P1: POS q/k/v projection (stride-2 conv as GEMM) ----------
__global__ __launch_bounds__(256) void k_pos_qkv(
    const float* __restrict__ x,
    const float* __restrict__ Wq, const float* __restrict__ bq,
    const float* __restrict__ Wk, const float* __restrict__ bk,
    const float* __restrict__ Wv, const float* __restrict__ bv,
    float* __restrict__ Q, float* __restrict__ K, float* __restrict__ V)
{
  const int ot = blockIdx.x, lt = blockIdx.y, b = blockIdx.z;
  const int tid = threadIdx.x;
  __shared__ float At[64][68];
  __shared__ float Bt[64][68];
  const int l0 = lt * 64, o0 = ot * 64;
  int base; const float* Wsel; const float* bsel;
  if (ot == 0)      { base = 0;   Wsel = Wq; bsel = bq; }
  else if (ot == 1) { base = 64;  Wsel = Wk; bsel = bk; }
  else              { base = 128; Wsel = Wv; bsel = bv; }
  const int lj = (tid & 15) * 4, oi = (tid >> 4) * 4;
  float acc[4][4] = {};
  const float* xb = x + (size_t)b * 256 * 4096;
  for (int kc = 0; kc < 1024; kc += 64) {
    #pragma unroll
    for (int e0 = 0; e0 < 16; ++e0) {
      int e = e0 * 256 + tid;
      int kk = e >> 6, ll = e & 63;
      int k = kc + kk;
      int c = k >> 2, uv = k & 3;
      int l = l0 + ll;
      int y = 2 * (l >> 5) + (uv >> 1), xx = 2 * (l & 31) + (uv & 1);
      At[kk][ll] = xb[((size_t)c << 12) + (y << 6) + xx];
    }
    #pragma unroll
    for (int e0 = 0; e0 < 16; ++e0) {
      int e = e0 * 256 + tid;
      int oo = e >> 6, kk = e & 63;
      Bt[kk][oo] = Wsel[(size_t)(o0 - base + oo) * 1024 + kc + kk];
    }
    __syncthreads();
    #pragma unroll 16
    for (int kk = 0; kk < 64; ++kk) {
      float a[4], w[4];
      *(float4*)a = *(const float4*)&At[kk][lj];
      *(float4*)w = *(const float4*)&Bt[kk][oi];
      #pragma unroll
      for (int ii = 0; ii < 4; ++ii)
        #pragma unroll
        for (int jj = 0; jj < 4; ++jj)
          acc[ii][jj] += w[ii] * a[jj];
    }
    __syncthreads();
  }
  #pragma unroll
  for (int ii = 0; ii < 4; ++ii) {
    const int o = o0 + oi + ii;
    const float bias = bsel[o - base];
    #pragma unroll
    for (int jj = 0; jj < 4; ++jj) {
      const int l = l0 + lj + jj;
      const float val = acc[ii][jj] + bias;
      if (o < 64) {
        int hh = o >> 3, e = o & 7;
        Q[((((size_t)b * 8 + hh) << 10) + l) * 8 + e] = val;
      } else if (o < 128) {
        int o2 = o - 64, hh = o2 >> 3, e = o2 & 7;
        K[((((size_t)b * 8 + hh) << 10) + l) * 8 + e] = val;
      } else {
        int o2 = o - 128, hh = o2 >> 5, d = o2 & 31;
        V[((((size_t)b * 8 + hh) << 10) + l) * 32 + d] = val;
      }
    }
  }
}

// ---------------- P2: POS attention (two-pass, scores in LDS) ---------------
__global__ __launch_bounds__(256) void k_pos_attn(
    const float* __restrict__ Q, const float* __restrict__ K,
    const float* __restrict__ V, float* __restrict__ op)
{
  const int qt = blockIdx.x, h = blockIdx.y, b = blockIdx.z;
  __shared__ float sc[16][1024];
  __shared__ float qs[16][8];
  __shared__ float rinv[16];
  const int tid = threadIdx.x;
  const size_t bh = (size_t)b * 8 + h;
  const float* Qb = Q + bh * 8192;
  const float* Kb = K + bh * 8192;
  const float* Vb = V + bh * 32768;
  if (tid < 128) qs[tid >> 3][tid & 7] = Qb[(size_t)(qt * 16 + (tid >> 3)) * 8 + (tid & 7)];
  __syncthreads();
  const float scale = 0.35355339059327373f;  // 8^-0.5
  #pragma unroll 4
  for (int it = 0; it < 64; ++it) {
    int idx = it * 256 + tid;
    int r = idx >> 10, k = idx & 1023;
    float4 k0 = *(const float4*)(Kb + (size_t)k * 8);
    float4 k1 = *(const float4*)(Kb + (size_t)k * 8 + 4);
    float4 q0 = *(const float4*)&qs[r][0];
    float4 q1 = *(const float4*)&qs[r][4];
    float s = q0.x * k0.x + q0.y * k0.y + q0.z * k0.z + q0.w * k0.w
            + q1.x * k1.x + q1.y * k1.y + q1.z * k1.z + q1.w * k1.w;
    sc[r][k] = s * scale;
  }
  __syncthreads();
  {
    int r = tid >> 4, c0 = tid & 15;
    float m = -1e30f;
    for (int k = c0; k < 1024; k += 16) m = fmaxf(m, sc[r][k]);
    #pragma unroll
    for (int off = 8; off; off >>= 1) m = fmaxf(m, __shfl_xor(m, off, 16));
    float sum = 0.f;
    for (int k = c0; k < 1024; k += 16) { float p = __expf(sc[r][k] - m); sc[r][k] = p; sum += p; }
    #pragma unroll
    for (int off = 8; off; off >>= 1) sum += __shfl_xor(sum, off, 16);
    if (c0 == 0) rinv[r] = 1.f / sum;
  }
  __syncthreads();
  const int rr = tid >> 5, d = tid & 31;
  float acc0 = 0.f, acc1 = 0.f;
  #pragma unroll 4
  for (int k = 0; k < 1024; k += 4) {
    float4 p0 = *(const float4*)&sc[rr][k];
    float4 p1 = *(const float4*)&sc[rr + 8][k];
    float v0 = Vb[(size_t)(k + 0) * 32 + d];
    float v1 = Vb[(size_t)(k + 1) * 32 + d];
    float v2 = Vb[(size_t)(k + 2) * 32 + d];
    float v3 = Vb[(size_t)(k + 3) * 32 + d];
    acc0 += p0.x * v0 + p0.y * v1 + p0.z * v2 + p0.w * v3;
    acc1 += p1.x * v0 + p1.y * v1 + p1.z * v2 + p1.w * v3;
  }
  const int l1 = qt * 16 + rr, l2 = l1 + 8;
  const size_t ch = (size_t)b * 256 + h * 32 + d;
  op[ch * 1024 + l1] = acc0 * rinv[rr];
  op[ch * 1024 + l2] = acc1 * rinv[rr + 8];
}

// ---------------- generic 3x3 pad-1 conv as im2col GEMM (P3 and fusion) -----
template <int S, int CIN>
__global__ __launch_bounds__(256) void k_conv3x3(
    const float* __restrict__ in, const float* __restrict__ W,
    const float* __restrict__ bias, float* __restrict__ out)
{
  constexpr int K = CIN * 9;
  const int lt = blockIdx.x, ot = blockIdx.y, b = blockIdx.z;
  const int l0 = lt * 64, o0 = ot * 64;
  __shared__ float At[64][68];
  __shared__ float Bt[64][68];
  const int tid = threadIdx.x;
  const int lj = (tid & 15) * 4, oi = (tid >> 4) * 4;
  float acc[4][4] = {};
  const float* inb = in + (size_t)b * CIN * S * S;
  for (int kc = 0; kc < K; kc += 64) {
    #pragma unroll
    for (int e0 = 0; e0 < 16; ++e0) {
      int e = e0 * 256 + tid;
      int kk = e >> 6, ll = e & 63;
      int k = kc + kk;
      int c = (int)((unsigned)k / 9u);
      int r9 = k - c * 9;
      int t3 = (int)((unsigned)r9 / 3u);
      int dy = t3 - 1, dx = r9 - t3 * 3 - 1;
      int l = l0 + ll;
      int y = l / S + dy, xx = l % S + dx;
      float v = 0.f;
      if ((unsigned)y < (unsigned)S && (unsigned)xx < (unsigned)S)
        v = inb[((size_t)c * S + y) * S + xx];
      At[kk][ll] = v;
    }
    #pragma unroll
    for (int e0 = 0; e0 < 16; ++e0) {
      int e = e0 * 256 + tid;
      int oo = e >> 6, kk = e & 63;
      Bt[kk][oo] = W[(size_t)(o0 + oo) * K + kc + kk];
    }
    __syncthreads();
    #pragma unroll 16
    for (int kk = 0; kk < 64; ++kk) {
      float a[4], w[4];
      *(float4*)a = *(const float4*)&At[kk][lj];
      *(float4*)w = *(const float4*)&Bt[kk][oi];
      #pragma unroll
      for (int ii = 0; ii < 4; ++ii)
        #pragma unroll
        for (int jj = 0; jj < 4; ++jj)
          acc[ii][jj] += w[ii] * a[jj];
    }
    __syncthreads();
  }
  #pragma unroll
  for (int ii = 0; ii < 4; ++ii) {
    const int o = o0 + oi + ii;
    const float bb = bias[o];
    #pragma unroll
    for (int jj = 0; jj < 4; ++jj) {
      const int l = l0 + lj + jj;
      out[((size_t)b * 256 + o) * (S * S) + l] = acc[ii][jj] + bb;
    }
  }
}

// ---------------- P4: bilinear x2 upsample + residual -> fused[0:256] -------
__global__ __launch_bounds__(256) void k_upsample(
    const float* __restrict__ xpos, const float* __restrict__ opc,
    const float* __restrict__ gamma, float* __restrict__ fused)
{
  const int idx = blockIdx.x * 256 + threadIdx.x;  // over 8*256*64*64
  const int xx = idx & 63, y = (idx >> 6) & 63, c = (idx >> 12) & 255, b = idx >> 20;
  const int my = y >> 1;
  const int y0 = (y & 1) ? my : my - 1;
  const float fy = (y & 1) ? 0.25f : 0.75f;
  const int mx = xx >> 1;
  const int x0 = (xx & 1) ? mx : mx - 1;
  const float fx = (xx & 1) ? 0.25f : 0.75f;
  const int y0c = max(y0, 0), y1c = min(y0 + 1, 31);
  const int x0c = max(x0, 0), x1c = min(x0 + 1, 31);
  const float* Pc = opc + ((size_t)b * 256 + c) * 1024;
  const float v00 = Pc[y0c * 32 + x0c], v01 = Pc[y0c * 32 + x1c];
  const float v10 = Pc[y1c * 32 + x0c], v11 = Pc[y1c * 32 + x1c];
  const float v = (1.f - fy) * ((1.f - fx) * v00 + fx * v01)
                + fy * ((1.f - fx) * v10 + fx * v11);
  fused[(size_t)idx + (size_t)b * 256 * 4096] = xpos[idx] + gamma[0] * v;
}

// ---------------- C1: CHA attention scores (on-the-fly q/k projection) ------
__global__ __launch_bounds__(256) void k_cha_scores(
    const float* __restrict__ x,
    const float* __restrict__ Wq, const float* __restrict__ bq,
    const float* __restrict__ Wk, const float* __restrict__ bk,
    float* __restrict__ S)
{
  const int tt = blockIdx.x, ct = tt >> 2, dt = tt & 3;
  const int h = blockIdx.y, b = blockIdx.z;
  const int gq0 = h * 32 + ct * 8, gk0 = h * 32 + dt * 8;
  __shared__ float Qt[64][68], Kt[64][68];
  __shared__ float wq_s[8][32], wk_s[8][32];
  __shared__ float bq_s[8][8], bk_s[8][8];
  const int tid = threadIdx.x;
  {
    int gl = tid >> 5, r = tid & 31;
    wq_s[gl][r] = Wq[(size_t)(gq0 + gl) * 32 + r];
    wk_s[gl][r] = Wk[(size_t)(gk0 + gl) * 32 + r];
    if (r < 8) {
      bq_s[gl][r] = bq[(size_t)(gq0 + gl) * 8 + r];
      bk_s[gl][r] = bk[(size_t)(gk0 + gl) * 8 + r];
    }
  }
  __syncthreads();
  float acc[4][4] = {};
  const int ci = (tid >> 4) * 4, dj = (tid & 15) * 4;
  const float* xb = x + (size_t)b * 256 * 4096;
  for (int lc = 0; lc < 1024; lc += 64) {
    #pragma unroll
    for (int e0 = 0; e0 < 16; ++e0) {
      int e = e0 * 256 + tid;
      int ll2 = e >> 6, cl = e & 63;
      int l = lc + ll2, i = l >> 5, j = l & 31;
      int gl = cl >> 3, hh = cl & 7;
      const float* pq = xb + (((size_t)(gq0 + gl)) * 64 + 2 * i) * 64 + 2 * j;
      Qt[ll2][cl] = pq[0] * wq_s[gl][hh * 4 + 0] + pq[1] * wq_s[gl][hh * 4 + 1]
                  + pq[64] * wq_s[gl][hh * 4 + 2] + pq[65] * wq_s[gl][hh * 4 + 3]
                  + bq_s[gl][hh];
      const float* pk = xb + (((size_t)(gk0 + gl)) * 64 + 2 * i) * 64 + 2 * j;
      Kt[ll2][cl] = pk[0] * wk_s[gl][hh * 4 + 0] + pk[1] * wk_s[gl][hh * 4 + 1]
                  + pk[64] * wk_s[gl][hh * 4 + 2] + pk[65] * wk_s[gl][hh * 4 + 3]
                  + bk_s[gl][hh];
    }
    __syncthreads();
    #pragma unroll 16
    for (int kk = 0; kk < 64; ++kk) {
      float a[4], w[4];
      *(float4*)a = *(const float4*)&Qt[kk][ci];
      *(float4*)w = *(const float4*)&Kt[kk][dj];
      #pragma unroll
      for (int ii = 0; ii < 4; ++ii)
        #pragma unroll
        for (int jj = 0; jj < 4; ++jj)
          acc[ii][jj] += a[ii] * w[jj];
    }
    __syncthreads();
  }
  const float scale = 0.03125f;  // 1024^-0.5
  const size_t base = (((size_t)b * 8 + h) * 256 + ct * 64) * 256 + dt * 64;
  #pragma unroll
  for (int ii = 0; ii < 4; ++ii)
    #pragma unroll
    for (int jj = 0; jj < 4; ++jj)
      S[base + (size_t)(ci + ii) * 256 + dj + jj] = acc[ii][jj] * scale;
}

// ---------------- C2: row softmax over 256 (one wave per row) ---------------
__global__ __launch_bounds__(256) void k_softmax256(float* __restrict__ S)
{
  const int row = blockIdx.x * 4 + (threadIdx.x >> 6);
  const int lane = threadIdx.x & 63;
  float* r = S + (size_t)row * 256;
  float4 v = *(float4*)(r + lane * 4);
  float m = fmaxf(fmaxf(v.x, v.y), fmaxf(v.z, v.w));
  #pragma unroll
  for (int off = 32; off; off >>= 1) m = fmaxf(m, __shfl_xor(m, off, 64));
  v.x = __expf(v.x - m); v.y = __expf(v.y - m);
  v.z = __expf(v.z - m); v.w = __expf(v.w - m);
  float s = v.x + v.y + v.z + v.w;
  #pragma unroll
  for (int off = 32; off; off >>= 1) s += __shfl_xor(s, off, 64);
  const float inv = 1.f / s;
  v.x *= inv; v.y *= inv; v.z *= inv; v.w *= inv;
  *(float4*)(r + lane * 4) = v;
}

// ------- C3: oc = P @ vc (vc on the fly) + grouped ConvT + residual ---------
__global__ __launch_bounds__(256) void k_cha_out(
    const float* __restrict__ x, const float* __restrict__ P,
    const float* __restrict__ Wv, const float* __restrict__ bv,
    const float* __restrict__ Wt, const float* __restrict__ bt,
    const float* __restrict__ gamma, float* __restrict__ fused)
{
  const int lt = blockIdx.x, ct = blockIdx.y;
  const int bh = blockIdx.z, b = bh >> 3, h = bh & 7;
  const int l0 = lt * 64, c0 = ct * 64;
  __shared__ float Pt[64][68], Vt[64][68];
  __shared__ float wv_s[32][32];
  __shared__ float bv_s[32][8];
  __shared__ float wt_s[8][32];
  __shared__ float bt_s[8];
  const int tid = threadIdx.x;
  const int gv0 = h * 32;
  #pragma unroll
  for (int e0 = 0; e0 < 4; ++e0) {
    int e = e0 * 256 + tid;
    wv_s[e >> 5][e & 31] = Wv[(size_t)(gv0 + (e >> 5)) * 32 + (e & 31)];
  }
  bv_s[tid >> 3][tid & 7] = bv[(size_t)(gv0 + (tid >> 3)) * 8 + (tid & 7)];
  wt_s[tid >> 5][tid & 31] = Wt[(size_t)(h * 32 + ct * 8 + (tid >> 5)) * 32 + (tid & 31)];
  if (tid < 8) bt_s[tid] = bt[h * 32 + ct * 8 + tid];
  __syncthreads();
  float acc[4][4] = {};
  const int ci = (tid >> 4) * 4, lj = (tid & 15) * 4;
  const float* xb = x + (size_t)b * 256 * 4096;
  const float* Pb = P + ((size_t)bh * 256 + c0) * 256;
  for (int dk = 0; dk < 256; dk += 64) {
    #pragma unroll
    for (int e0 = 0; e0 < 16; ++e0) {
      int e = e0 * 256 + tid;
      int cl = e >> 6, dd = e & 63;
      Pt[dd][cl] = Pb[(size_t)cl * 256 + dk + dd];
    }
    #pragma unroll
    for (int e0 = 0; e0 < 16; ++e0) {
      int e = e0 * 256 + tid;
      int dd = e >> 6, ll = e & 63;
      int d = dk + dd;
      int gvl = d >> 3, hv = d & 7;
      int l = l0 + ll, i = l >> 5, j = l & 31;
      const float* pv = xb + (((size_t)(gv0 + gvl)) * 64 + 2 * i) * 64 + 2 * j;
      Vt[dd][ll] = pv[0] * wv_s[gvl][hv * 4 + 0] + pv[1] * wv_s[gvl][hv * 4 + 1]
                 + pv[64] * wv_s[gvl][hv * 4 + 2] + pv[65] * wv_s[gvl][hv * 4 + 3]
                 + bv_s[gvl][hv];
    }
    __syncthreads();
    #pragma unroll 16
    for (int kk = 0; kk < 64; ++kk) {
      float a[4], w[4];
      *(float4*)a = *(const float4*)&Pt[kk][ci];
      *(float4*)w = *(const float4*)&Vt[kk][lj];
      #pragma unroll
      for (int ii = 0; ii < 4; ++ii)
        #pragma unroll
        for (int jj = 0; jj < 4; ++jj)
          acc[ii][jj] += a[ii] * w[jj];
    }
    __syncthreads();
  }
  // stash oc tile into Pt (reuse) for the cross-thread ConvTranspose epilogue
  #pragma unroll
  for (int ii = 0; ii < 4; ++ii)
    #pragma unroll
    for (int jj = 0; jj < 4; ++jj)
      Pt[ci + ii][lj + jj] = acc[ii][jj];
  __syncthreads();
  const float gm = gamma[0];
  #pragma unroll
  for (int e0 = 0; e0 < 8; ++e0) {
    int e = e0 * 256 + tid;
    int ll = e & 63, uv = (e >> 6) & 3, gl = e >> 8;
    float v = bt_s[gl];
    #pragma unroll
    for (int i2 = 0; i2 < 8; ++i2) v += Pt[gl * 8 + i2][ll] * wt_s[gl][i2 * 4 + uv];
    int g = h * 32 + ct * 8 + gl;
    int l = l0 + ll, p = l >> 5, q = l & 31;
    int y = 2 * p + (uv >> 1), xx2 = 2 * q + (uv & 1);
    size_t sp = ((size_t)g * 64 + y) * 64 + xx2;
    float res = xb[sp] + gm * v;
    fused[(((size_t)b * 512 + 256 + g) * 64 + y) * 64 + xx2] = res;
  }
}

extern "C" void kernel_launch(void* const* d_in, const int* in_sizes, int n_in,
                              void* d_out, int out_size, void* d_ws, size_t ws_size,
                              hipStream_t stream)
{
  (void)in_sizes; (void)n_in; (void)out_size; (void)ws_size;
  const float* qkv_pos   = (const float*)d_in[0];
  const float* qkv_cha   = (const float*)d_in[1];
  const float* Wq_pos    = (const float*)d_in[2];
  const float* bq_pos    = (const float*)d_in[3];
  const float* Wk_pos    = (const float*)d_in[4];
  const float* bk_pos    = (const float*)d_in[5];
  const float* Wv_pos    = (const float*)d_in[6];
  const float* bv_pos    = (const float*)d_in[7];
  const float* Wo_pos    = (const float*)d_in[8];
  const float* bo_pos    = (const float*)d_in[9];
  const float* gamma_pos = (const float*)d_in[10];
  const float* Wq_cha    = (const float*)d_in[11];
  const float* bq_cha    = (const float*)d_in[12];
  const float* Wk_cha    = (const float*)d_in[13];
  const float* bk_cha    = (const float*)d_in[14];
  const float* Wv_cha    = (const float*)d_in[15];
  const float* bv_cha    = (const float*)d_in[16];
  const float* Wt_cha    = (const float*)d_in[17];
  const float* bt_cha    = (const float*)d_in[18];
  const float* gamma_cha = (const float*)d_in[19];
  const float* Wf        = (const float*)d_in[20];
  const float* bf        = (const float*)d_in[21];
  float* out = (float*)d_out;

  float* ws      = (float*)d_ws;
  float* Qp      = ws;
  float* Kp      = Qp + 524288;
  float* Vp      = Kp + 524288;
  float* op_attn = Vp + 2097152;
  float* op_conv = op_attn + 2097152;
  float* attn_c  = op_conv + 2097152;
  float* fused   = attn_c + 4194304;

  // POS branch
  k_pos_qkv<<<dim3(6, 16, 8), 256, 0, stream>>>(qkv_pos, Wq_pos, bq_pos,
      Wk_pos, bk_pos, Wv_pos, bv_pos, Qp, Kp, Vp);
  k_pos_attn<<<dim3(64, 8, 8), 256, 0, stream>>>(Qp, Kp, Vp, op_attn);
  k_conv3x3<32, 256><<<dim3(16, 4, 8), 256, 0, stream>>>(op_attn, Wo_pos, bo_pos, op_conv);
  k_upsample<<<dim3(32768), 256, 0, stream>>>(qkv_pos, op_conv, gamma_pos, fused);
  // CHA branch
  k_cha_scores<<<dim3(16, 8, 8), 256, 0, stream>>>(qkv_cha, Wq_cha, bq_cha,
      Wk_cha, bk_cha, attn_c);
  k_softmax256<<<dim3(4096), 256, 0, stream>>>(attn_c);
  k_cha_out<<<dim3(16, 4, 64), 256, 0, stream>>>(qkv_cha, attn_c, Wv_cha, bv_cha,
      Wt_cha, bt_cha, gamma_cha, fused);
  // fusion conv
  k_conv3x3<64, 512><<<dim3(64, 4, 8), 256, 0, stream>>>(fused, Wf, bf, out);
}

// Round 2
// 1551.277 us; speedup vs baseline: 1.8265x; 1.8265x over previous
//
#include <hip/hip_runtime.h>
#include <math.h>

// Shapes: B=8, C=256, H=W=64, HQ=WQ=32, L=1024, NH=8, hd=8, dv=32
// Workspace layout (float units):
//   Wpf  bf16[256*4608]  -> 589824 f
//   Wpo  bf16[256*2304]  -> 294912 f
//   Qp   f32 [524288]
//   Kp   f32 [524288]
//   Vp   f32 [2097152]
//   op_attn bf16[2097152] -> 1048576 f
//   op_conv f32 [2097152]
//   attn_c  f32 [4194304]
//   fused   bf16[16777216] -> 8388608 f
// total ~= 79 MB

typedef __attribute__((ext_vector_type(8))) short bf16x8;   // 8 bf16 (guide-blessed)
typedef __attribute__((ext_vector_type(4))) float f32x4;

__device__ __forceinline__ ushort f2bf(float f) {
  union { float f; unsigned u; } v; v.f = f;
  unsigned r = (v.u + 0x7FFFu + ((v.u >> 16) & 1u)) >> 16;
  return (ushort)r;
}

// ---------------- cast fp32 -> bf16 (weight pre-pack) -----------------------
__global__ __launch_bounds__(256) void k_cast_bf16(
    const float* __restrict__ in, ushort* __restrict__ out, int n)
{
  int i = blockIdx.x * 256 + threadIdx.x;
  if (i < n) out[i] = f2bf(in[i]);
}

// ---------------- P1: POS q/k/v projection (stride-2 conv as GEMM) ----------
__global__ __launch_bounds__(256) void k_pos_qkv(
    const float* __restrict__ x,
    const float* __restrict__ Wq, const float* __restrict__ bq,
    const float* __restrict__ Wk, const float* __restrict__ bk,
    const float* __restrict__ Wv, const float* __restrict__ bv,
    float* __restrict__ Q, float* __restrict__ K, float* __restrict__ V)
{
  const int ot = blockIdx.x, lt = blockIdx.y, b = blockIdx.z;
  const int tid = threadIdx.x;
  __shared__ float At[64][68];
  __shared__ float Bt[64][68];
  const int l0 = lt * 64, o0 = ot * 64;
  int base; const float* Wsel; const float* bsel;
  if (ot == 0)      { base = 0;   Wsel = Wq; bsel = bq; }
  else if (ot == 1) { base = 64;  Wsel = Wk; bsel = bk; }
  else              { base = 128; Wsel = Wv; bsel = bv; }
  const int lj = (tid & 15) * 4, oi = (tid >> 4) * 4;
  float acc[4][4] = {};
  const float* xb = x + (size_t)b * 256 * 4096;
  for (int kc = 0; kc < 1024; kc += 64) {
    #pragma unroll
    for (int e0 = 0; e0 < 16; ++e0) {
      int e = e0 * 256 + tid;
      int kk = e >> 6, ll = e & 63;
      int k = kc + kk;
      int c = k >> 2, uv = k & 3;
      int l = l0 + ll;
      int y = 2 * (l >> 5) + (uv >> 1), xx = 2 * (l & 31) + (uv & 1);
      At[kk][ll] = xb[((size_t)c << 12) + (y << 6) + xx];
    }
    #pragma unroll
    for (int e0 = 0; e0 < 16; ++e0) {
      int e = e0 * 256 + tid;
      int oo = e >> 6, kk = e & 63;
      Bt[kk][oo] = Wsel[(size_t)(o0 - base + oo) * 1024 + kc + kk];
    }
    __syncthreads();
    #pragma unroll 16
    for (int kk = 0; kk < 64; ++kk) {
      float a[4], w[4];
      *(float4*)a = *(const float4*)&At[kk][lj];
      *(float4*)w = *(const float4*)&Bt[kk][oi];
      #pragma unroll
      for (int ii = 0; ii < 4; ++ii)
        #pragma unroll
        for (int jj = 0; jj < 4; ++jj)
          acc[ii][jj] += w[ii] * a[jj];
    }
    __syncthreads();
  }
  #pragma unroll
  for (int ii = 0; ii < 4; ++ii) {
    const int o = o0 + oi + ii;
    const float bias = bsel[o - base];
    #pragma unroll
    for (int jj = 0; jj < 4; ++jj) {
      const int l = l0 + lj + jj;
      const float val = acc[ii][jj] + bias;
      if (o < 64) {
        int hh = o >> 3, e = o & 7;
        Q[((((size_t)b * 8 + hh) << 10) + l) * 8 + e] = val;
      } else if (o < 128) {
        int o2 = o - 64, hh = o2 >> 3, e = o2 & 7;
        K[((((size_t)b * 8 + hh) << 10) + l) * 8 + e] = val;
      } else {
        int o2 = o - 128, hh = o2 >> 5, d = o2 & 31;
        V[((((size_t)b * 8 + hh) << 10) + l) * 32 + d] = val;
      }
    }
  }
}

// ---------------- P2: POS attention (two-pass, scores in LDS) ---------------
__global__ __launch_bounds__(256) void k_pos_attn(
    const float* __restrict__ Q, const float* __restrict__ K,
    const float* __restrict__ V, ushort* __restrict__ op)
{
  const int qt = blockIdx.x, h = blockIdx.y, b = blockIdx.z;
  __shared__ float sc[16][1024];
  __shared__ float qs[16][8];
  __shared__ float rinv[16];
  const int tid = threadIdx.x;
  const size_t bh = (size_t)b * 8 + h;
  const float* Qb = Q + bh * 8192;
  const float* Kb = K + bh * 8192;
  const float* Vb = V + bh * 32768;
  if (tid < 128) qs[tid >> 3][tid & 7] = Qb[(size_t)(qt * 16 + (tid >> 3)) * 8 + (tid & 7)];
  __syncthreads();
  const float scale = 0.35355339059327373f;  // 8^-0.5
  #pragma unroll 4
  for (int it = 0; it < 64; ++it) {
    int idx = it * 256 + tid;
    int r = idx >> 10, k = idx & 1023;
    float4 k0 = *(const float4*)(Kb + (size_t)k * 8);
    float4 k1 = *(const float4*)(Kb + (size_t)k * 8 + 4);
    float4 q0 = *(const float4*)&qs[r][0];
    float4 q1 = *(const float4*)&qs[r][4];
    float s = q0.x * k0.x + q0.y * k0.y + q0.z * k0.z + q0.w * k0.w
            + q1.x * k1.x + q1.y * k1.y + q1.z * k1.z + q1.w * k1.w;
    sc[r][k] = s * scale;
  }
  __syncthreads();
  {
    int r = tid >> 4, c0 = tid & 15;
    float m = -1e30f;
    for (int k = c0; k < 1024; k += 16) m = fmaxf(m, sc[r][k]);
    #pragma unroll
    for (int off = 8; off; off >>= 1) m = fmaxf(m, __shfl_xor(m, off, 16));
    float sum = 0.f;
    for (int k = c0; k < 1024; k += 16) { float p = __expf(sc[r][k] - m); sc[r][k] = p; sum += p; }
    #pragma unroll
    for (int off = 8; off; off >>= 1) sum += __shfl_xor(sum, off, 16);
    if (c0 == 0) rinv[r] = 1.f / sum;
  }
  __syncthreads();
  const int rr = tid >> 5, d = tid & 31;
  float acc0 = 0.f, acc1 = 0.f;
  #pragma unroll 4
  for (int k = 0; k < 1024; k += 4) {
    float4 p0 = *(const float4*)&sc[rr][k];
    float4 p1 = *(const float4*)&sc[rr + 8][k];
    float v0 = Vb[(size_t)(k + 0) * 32 + d];
    float v1 = Vb[(size_t)(k + 1) * 32 + d];
    float v2 = Vb[(size_t)(k + 2) * 32 + d];
    float v3 = Vb[(size_t)(k + 3) * 32 + d];
    acc0 += p0.x * v0 + p0.y * v1 + p0.z * v2 + p0.w * v3;
    acc1 += p1.x * v0 + p1.y * v1 + p1.z * v2 + p1.w * v3;
  }
  const int l1 = qt * 16 + rr, l2 = l1 + 8;
  const size_t ch = (size_t)b * 256 + h * 32 + d;
  op[ch * 1024 + l1] = f2bf(acc0 * rinv[rr]);
  op[ch * 1024 + l2] = f2bf(acc1 * rinv[rr + 8]);
}

// ------- 3x3 pad-1 conv, bf16 MFMA implicit GEMM (Wo conv & fusion conv) ----
// in: bf16 [b][CIN][S][S]; Wp: bf16 [256][CIN*9] (k = c*9 + ky*3 + kx);
// out: fp32 [b][256][S*S]
template <int S, int CIN>
__global__ __launch_bounds__(256) void k_conv3x3_mfma(
    const ushort* __restrict__ in, const ushort* __restrict__ Wp,
    const float* __restrict__ bias, float* __restrict__ out)
{
  constexpr int K = CIN * 9;
  constexpr int NSP = S * S;
  const int n0 = blockIdx.x * 128, oc0 = blockIdx.y * 128, b = blockIdx.z;
  const int tid = threadIdx.x;
  const int lane = tid & 63, w = tid >> 6;
  __shared__ ushort As[128][32];   // [oc_local][k_local], 64B rows
  __shared__ ushort Bs[128][40];   // [n_local][k_local], 80B rows (padded)
  const ushort* inb = in + (size_t)b * CIN * NSP;
  const int wr = w >> 1, wc = w & 1;   // wave tile: 64 oc x 64 n
  f32x4 acc[4][4];
  #pragma unroll
  for (int mi = 0; mi < 4; ++mi)
    #pragma unroll
    for (int ni = 0; ni < 4; ++ni) {
      f32x4 z = {0.f, 0.f, 0.f, 0.f};
      acc[mi][ni] = z;
    }
  // B gather: thread -> (n_local = tid>>1, k half = (tid&1)*16)
  const int nloc = tid >> 1;
  const int n_g = n0 + nloc;
  const int yb = n_g / S, xb = n_g % S;
  const int kpart = (tid & 1) * 16;
  const char* wbase = (const char*)Wp;

  for (int kc = 0; kc < K; kc += 32) {
    __syncthreads();   // previous compute done before LDS overwrite
    // A: async global->LDS, 16B/lane, 2 instrs per wave = 8 KB
    #pragma unroll
    for (int q = 0; q < 2; ++q) {
      int idx = w * 128 + q * 64 + lane;          // 16B unit index 0..511
      int ocr = idx >> 2, inner = (idx & 3) * 16; // row + byte-in-row
      const char* src = wbase + ((size_t)(oc0 + ocr) * K + kc) * 2 + inner;
      char* dst = (char*)&As[0][0] + w * 2048 + q * 1024; // wave-uniform
      __builtin_amdgcn_global_load_lds(
          (const __attribute__((address_space(1))) unsigned*)src,
          (__attribute__((address_space(3))) unsigned*)dst, 16, 0, 0);
    }
    // B: gather 16 im2col elems (8 contiguous k per b128 write)
    union { uint4 q[2]; ushort s[16]; } vals;
    int k0 = kc + kpart;
    unsigned c = (unsigned)k0 / 9u;
    int t9 = k0 - (int)c * 9;
    #pragma unroll
    for (int j = 0; j < 16; ++j) {
      int t3 = (t9 >= 6) ? 2 : (t9 >= 3) ? 1 : 0;
      int dy = t3 - 1, dx = t9 - t3 * 3 - 1;
      int y = yb + dy, x = xb + dx;
      ushort v = 0;
      if ((unsigned)y < (unsigned)S && (unsigned)x < (unsigned)S)
        v = inb[(size_t)c * NSP + y * S + x];
      vals.s[j] = v;
      if (++t9 == 9) { t9 = 0; ++c; }
    }
    *(uint4*)&Bs[nloc][kpart] = vals.q[0];
    *(uint4*)&Bs[nloc][kpart + 8] = vals.q[1];
    __syncthreads();
    // compute: 16 MFMA per wave
    bf16x8 af[4], bfv[4];
    #pragma unroll
    for (int mi = 0; mi < 4; ++mi)
      af[mi] = *(const bf16x8*)&As[wr * 64 + mi * 16 + (lane & 15)][(lane >> 4) * 8];
    #pragma unroll
    for (int ni = 0; ni < 4; ++ni)
      bfv[ni] = *(const bf16x8*)&Bs[wc * 64 + ni * 16 + (lane & 15)][(lane >> 4) * 8];
    #pragma unroll
    for (int mi = 0; mi < 4; ++mi)
      #pragma unroll
      for (int ni = 0; ni < 4; ++ni)
        acc[mi][ni] = __builtin_amdgcn_mfma_f32_16x16x32_bf16(
            af[mi], bfv[ni], acc[mi][ni], 0, 0, 0);
  }
  // epilogue: C/D layout col=lane&15 (n), row=(lane>>4)*4+r (oc)
  float* outb = out + (size_t)b * 256 * NSP;
  #pragma unroll
  for (int mi = 0; mi < 4; ++mi) {
    #pragma unroll
    for (int r = 0; r < 4; ++r) {
      int oc = oc0 + wr * 64 + mi * 16 + (lane >> 4) * 4 + r;
      float bb = bias[oc];
      #pragma unroll
      for (int ni = 0; ni < 4; ++ni) {
        int n = n0 + wc * 64 + ni * 16 + (lane & 15);
        outb[(size_t)oc * NSP + n] = acc[mi][ni][r] + bb;
      }
    }
  }
}

// ---------------- P4: bilinear x2 upsample + residual -> fused[0:256] -------
__global__ __launch_bounds__(256) void k_upsample(
    const float* __restrict__ xpos, const float* __restrict__ opc,
    const float* __restrict__ gamma, ushort* __restrict__ fused)
{
  const int idx = blockIdx.x * 256 + threadIdx.x;  // over 8*256*64*64
  const int xx = idx & 63, y = (idx >> 6) & 63, c = (idx >> 12) & 255, b = idx >> 20;
  const int my = y >> 1;
  const int y0 = (y & 1) ? my : my - 1;
  const float fy = (y & 1) ? 0.25f : 0.75f;
  const int mx = xx >> 1;
  const int x0 = (xx & 1) ? mx : mx - 1;
  const float fx = (xx & 1) ? 0.25f : 0.75f;
  const int y0c = max(y0, 0), y1c = min(y0 + 1, 31);
  const int x0c = max(x0, 0), x1c = min(x0 + 1, 31);
  const float* Pc = opc + ((size_t)b * 256 + c) * 1024;
  const float v00 = Pc[y0c * 32 + x0c], v01 = Pc[y0c * 32 + x1c];
  const float v10 = Pc[y1c * 32 + x0c], v11 = Pc[y1c * 32 + x1c];
  const float v = (1.f - fy) * ((1.f - fx) * v00 + fx * v01)
                + fy * ((1.f - fx) * v10 + fx * v11);
  fused[(size_t)idx + (size_t)b * 256 * 4096] = f2bf(xpos[idx] + gamma[0] * v);
}

// ---------------- C1: CHA attention scores (on-the-fly q/k projection) ------
__global__ __launch_bounds__(256) void k_cha_scores(
    const float* __restrict__ x,
    const float* __restrict__ Wq, const float* __restrict__ bq,
    const float* __restrict__ Wk, const float* __restrict__ bk,
    float* __restrict__ S)
{
  const int tt = blockIdx.x, ct = tt >> 2, dt = tt & 3;
  const int h = blockIdx.y, b = blockIdx.z;
  const int gq0 = h * 32 + ct * 8, gk0 = h * 32 + dt * 8;
  __shared__ float Qt[64][68], Kt[64][68];
  __shared__ float wq_s[8][32], wk_s[8][32];
  __shared__ float bq_s[8][8], bk_s[8][8];
  const int tid = threadIdx.x;
  {
    int gl = tid >> 5, r = tid & 31;
    wq_s[gl][r] = Wq[(size_t)(gq0 + gl) * 32 + r];
    wk_s[gl][r] = Wk[(size_t)(gk0 + gl) * 32 + r];
    if (r < 8) {
      bq_s[gl][r] = bq[(size_t)(gq0 + gl) * 8 + r];
      bk_s[gl][r] = bk[(size_t)(gk0 + gl) * 8 + r];
    }
  }
  __syncthreads();
  float acc[4][4] = {};
  const int ci = (tid >> 4) * 4, dj = (tid & 15) * 4;
  const float* xb = x + (size_t)b * 256 * 4096;
  for (int lc = 0; lc < 1024; lc += 64) {
    #pragma unroll
    for (int e0 = 0; e0 < 16; ++e0) {
      int e = e0 * 256 + tid;
      int ll2 = e >> 6, cl = e & 63;
      int l = lc + ll2, i = l >> 5, j = l & 31;
      int gl = cl >> 3, hh = cl & 7;
      const float* pq = xb + (((size_t)(gq0 + gl)) * 64 + 2 * i) * 64 + 2 * j;
      Qt[ll2][cl] = pq[0] * wq_s[gl][hh * 4 + 0] + pq[1] * wq_s[gl][hh * 4 + 1]
                  + pq[64] * wq_s[gl][hh * 4 + 2] + pq[65] * wq_s[gl][hh * 4 + 3]
                  + bq_s[gl][hh];
      const float* pk = xb + (((size_t)(gk0 + gl)) * 64 + 2 * i) * 64 + 2 * j;
      Kt[ll2][cl] = pk[0] * wk_s[gl][hh * 4 + 0] + pk[1] * wk_s[gl][hh * 4 + 1]
                  + pk[64] * wk_s[gl][hh * 4 + 2] + pk[65] * wk_s[gl][hh * 4 + 3]
                  + bk_s[gl][hh];
    }
    __syncthreads();
    #pragma unroll 16
    for (int kk = 0; kk < 64; ++kk) {
      float a[4], w[4];
      *(float4*)a = *(const float4*)&Qt[kk][ci];
      *(float4*)w = *(const float4*)&Kt[kk][dj];
      #pragma unroll
      for (int ii = 0; ii < 4; ++ii)
        #pragma unroll
        for (int jj = 0; jj < 4; ++jj)
          acc[ii][jj] += a[ii] * w[jj];
    }
    __syncthreads();
  }
  const float scale = 0.03125f;  // 1024^-0.5
  const size_t base = (((size_t)b * 8 + h) * 256 + ct * 64) * 256 + dt * 64;
  #pragma unroll
  for (int ii = 0; ii < 4; ++ii)
    #pragma unroll
    for (int jj = 0; jj < 4; ++jj)
      S[base + (size_t)(ci + ii) * 256 + dj + jj] = acc[ii][jj] * scale;
}

// ---------------- C2: row softmax over 256 (one wave per row) ---------------
__global__ __launch_bounds__(256) void k_softmax256(float* __restrict__ S)
{
  const int row = blockIdx.x * 4 + (threadIdx.x >> 6);
  const int lane = threadIdx.x & 63;
  float* r = S + (size_t)row * 256;
  float4 v = *(float4*)(r + lane * 4);
  float m = fmaxf(fmaxf(v.x, v.y), fmaxf(v.z, v.w));
  #pragma unroll
  for (int off = 32; off; off >>= 1) m = fmaxf(m, __shfl_xor(m, off, 64));
  v.x = __expf(v.x - m); v.y = __expf(v.y - m);
  v.z = __expf(v.z - m); v.w = __expf(v.w - m);
  float s = v.x + v.y + v.z + v.w;
  #pragma unroll
  for (int off = 32; off; off >>= 1) s += __shfl_xor(s, off, 64);
  const float inv = 1.f / s;
  v.x *= inv; v.y *= inv; v.z *= inv; v.w *= inv;
  *(float4*)(r + lane * 4) = v;
}

// ------- C3: oc = P @ vc (vc on the fly) + grouped ConvT + residual ---------
__global__ __launch_bounds__(256) void k_cha_out(
    const float* __restrict__ x, const float* __restrict__ P,
    const float* __restrict__ Wv, const float* __restrict__ bv,
    const float* __restrict__ Wt, const float* __restrict__ bt,
    const float* __restrict__ gamma, ushort* __restrict__ fused)
{
  const int lt = blockIdx.x, ct = blockIdx.y;
  const int bh = blockIdx.z, b = bh >> 3, h = bh & 7;
  const int l0 = lt * 64, c0 = ct * 64;
  __shared__ float Pt[64][68], Vt[64][68];
  __shared__ float wv_s[32][32];
  __shared__ float bv_s[32][8];
  __shared__ float wt_s[8][32];
  __shared__ float bt_s[8];
  const int tid = threadIdx.x;
  const int gv0 = h * 32;
  #pragma unroll
  for (int e0 = 0; e0 < 4; ++e0) {
    int e = e0 * 256 + tid;
    wv_s[e >> 5][e & 31] = Wv[(size_t)(gv0 + (e >> 5)) * 32 + (e & 31)];
  }
  bv_s[tid >> 3][tid & 7] = bv[(size_t)(gv0 + (tid >> 3)) * 8 + (tid & 7)];
  wt_s[tid >> 5][tid & 31] = Wt[(size_t)(h * 32 + ct * 8 + (tid >> 5)) * 32 + (tid & 31)];
  if (tid < 8) bt_s[tid] = bt[h * 32 + ct * 8 + tid];
  __syncthreads();
  float acc[4][4] = {};
  const int ci = (tid >> 4) * 4, lj = (tid & 15) * 4;
  const float* xb = x + (size_t)b * 256 * 4096;
  const float* Pb = P + ((size_t)bh * 256 + c0) * 256;
  for (int dk = 0; dk < 256; dk += 64) {
    #pragma unroll
    for (int e0 = 0; e0 < 16; ++e0) {
      int e = e0 * 256 + tid;
      int cl = e >> 6, dd = e & 63;
      Pt[dd][cl] = Pb[(size_t)cl * 256 + dk + dd];
    }
    #pragma unroll
    for (int e0 = 0; e0 < 16; ++e0) {
      int e = e0 * 256 + tid;
      int dd = e >> 6, ll = e & 63;
      int d = dk + dd;
      int gvl = d >> 3, hv = d & 7;
      int l = l0 + ll, i = l >> 5, j = l & 31;
      const float* pv = xb + (((size_t)(gv0 + gvl)) * 64 + 2 * i) * 64 + 2 * j;
      Vt[dd][ll] = pv[0] * wv_s[gvl][hv * 4 + 0] + pv[1] * wv_s[gvl][hv * 4 + 1]
                 + pv[64] * wv_s[gvl][hv * 4 + 2] + pv[65] * wv_s[gvl][hv * 4 + 3]
                 + bv_s[gvl][hv];
    }
    __syncthreads();
    #pragma unroll 16
    for (int kk = 0; kk < 64; ++kk) {
      float a[4], w[4];
      *(float4*)a = *(const float4*)&Pt[kk][ci];
      *(float4*)w = *(const float4*)&Vt[kk][lj];
      #pragma unroll
      for (int ii = 0; ii < 4; ++ii)
        #pragma unroll
        for (int jj = 0; jj < 4; ++jj)
          acc[ii][jj] += a[ii] * w[jj];
    }
    __syncthreads();
  }
  #pragma unroll
  for (int ii = 0; ii < 4; ++ii)
    #pragma unroll
    for (int jj = 0; jj < 4; ++jj)
      Pt[ci + ii][lj + jj] = acc[ii][jj];
  __syncthreads();
  const float gm = gamma[0];
  #pragma unroll
  for (int e0 = 0; e0 < 8; ++e0) {
    int e = e0 * 256 + tid;
    int ll = e & 63, uv = (e >> 6) & 3, gl = e >> 8;
    float v = bt_s[gl];
    #pragma unroll
    for (int i2 = 0; i2 < 8; ++i2) v += Pt[gl * 8 + i2][ll] * wt_s[gl][i2 * 4 + uv];
    int g = h * 32 + ct * 8 + gl;
    int l = l0 + ll, p = l >> 5, q = l & 31;
    int y = 2 * p + (uv >> 1), xx2 = 2 * q + (uv & 1);
    size_t sp = ((size_t)g * 64 + y) * 64 + xx2;
    float res = xb[sp] + gm * v;
    fused[(((size_t)b * 512 + 256 + g) * 64 + y) * 64 + xx2] = f2bf(res);
  }
}

extern "C" void kernel_launch(void* const* d_in, const int* in_sizes, int n_in,
                              void* d_out, int out_size, void* d_ws, size_t ws_size,
                              hipStream_t stream)
{
  (void)in_sizes; (void)n_in; (void)out_size; (void)ws_size;
  const float* qkv_pos   = (const float*)d_in[0];
  const float* qkv_cha   = (const float*)d_in[1];
  const float* Wq_pos    = (const float*)d_in[2];
  const float* bq_pos    = (const float*)d_in[3];
  const float* Wk_pos    = (const float*)d_in[4];
  const float* bk_pos    = (const float*)d_in[5];
  const float* Wv_pos    = (const float*)d_in[6];
  const float* bv_pos    = (const float*)d_in[7];
  const float* Wo_pos    = (const float*)d_in[8];
  const float* bo_pos    = (const float*)d_in[9];
  const float* gamma_pos = (const float*)d_in[10];
  const float* Wq_cha    = (const float*)d_in[11];
  const float* bq_cha    = (const float*)d_in[12];
  const float* Wk_cha    = (const float*)d_in[13];
  const float* bk_cha    = (const float*)d_in[14];
  const float* Wv_cha    = (const float*)d_in[15];
  const float* bv_cha    = (const float*)d_in[16];
  const float* Wt_cha    = (const float*)d_in[17];
  const float* bt_cha    = (const float*)d_in[18];
  const float* gamma_cha = (const float*)d_in[19];
  const float* Wf        = (const float*)d_in[20];
  const float* bf        = (const float*)d_in[21];
  float* out = (float*)d_out;

  float* ws = (float*)d_ws;
  ushort* Wpf     = (ushort*)ws;                    // 1179648 bf16 = 589824 f
  ushort* Wpo     = (ushort*)(ws + 589824);         //  589824 bf16 = 294912 f
  float*  Qp      = ws + 884736;
  float*  Kp      = Qp + 524288;
  float*  Vp      = Kp + 524288;
  ushort* op_attn = (ushort*)(Vp + 2097152);        // 2097152 bf16
  float*  op_conv = Vp + 2097152 + 1048576;
  float*  attn_c  = op_conv + 2097152;
  ushort* fusedb  = (ushort*)(attn_c + 4194304);    // 16777216 bf16

  // weight pre-pack (bf16)
  k_cast_bf16<<<dim3(4608), 256, 0, stream>>>(Wf, Wpf, 1179648);
  k_cast_bf16<<<dim3(2304), 256, 0, stream>>>(Wo_pos, Wpo, 589824);
  // POS branch
  k_pos_qkv<<<dim3(6, 16, 8), 256, 0, stream>>>(qkv_pos, Wq_pos, bq_pos,
      Wk_pos, bk_pos, Wv_pos, bv_pos, Qp, Kp, Vp);
  k_pos_attn<<<dim3(64, 8, 8), 256, 0, stream>>>(Qp, Kp, Vp, op_attn);
  k_conv3x3_mfma<32, 256><<<dim3(8, 2, 8), 256, 0, stream>>>(op_attn, Wpo, bo_pos, op_conv);
  k_upsample<<<dim3(32768), 256, 0, stream>>>(qkv_pos, op_conv, gamma_pos, fusedb);
  // CHA branch
  k_cha_scores<<<dim3(16, 8, 8), 256, 0, stream>>>(qkv_cha, Wq_cha, bq_cha,
      Wk_cha, bk_cha, attn_c);
  k_softmax256<<<dim3(4096), 256, 0, stream>>>(attn_c);
  k_cha_out<<<dim3(16, 4, 64), 256, 0, stream>>>(qkv_cha, attn_c, Wv_cha, bv_cha,
      Wt_cha, bt_cha, gamma_cha, fusedb);
  // fusion conv (bf16 MFMA)
  k_conv3x3_mfma<64, 512><<<dim3(32, 2, 8), 256, 0, stream>>>(fusedb, Wpf, bf, out);
}

// Round 3
// 1159.294 us; speedup vs baseline: 2.4440x; 1.3381x over previous
//
#include <hip/hip_runtime.h>
#include <math.h>

// Shapes: B=8, C=256, H=W=64, HQ=WQ=32, L=1024, NH=8, hd=8, dv=32
//
// Workspace (float units), total 25,001,984 f = 100 MB:
//   Wpf  bf16[256*4608]            @ 0          (589824 f)
//   Wpo  bf16[256*2304]            @ 589824     (294912 f)
//   region2 (POS scratch, later aliased by CHA scratch) @ 884736, 15728640 f
//     POS:  Qp f32 @884736 (524288) | Kp @1409024 (524288) | Vp @1933312 (2097152)
//           op_attn bf16 @4030464 (1048576 f) | op_conv f32 @5079040 (2097152)
//     CHA (per half-batch of 4 b):
//           qcb bf16 @884736  (4194304 f) | kcb @5079040 (4194304 f)
//           vcT bf16 @9273344 (4194304 f) | attn_c f32 @13467648 (2097152 f)
//           P  bf16  @15564800 (1048576 f)
//   fused bf16[8*512*4096]         @ 16613376   (8388608 f)

typedef __attribute__((ext_vector_type(8))) short bf16x8;
typedef __attribute__((ext_vector_type(4))) float f32x4;

__device__ __forceinline__ ushort f2bf(float f) {
  union { float f; unsigned u; } v; v.f = f;
  unsigned r = (v.u + 0x7FFFu + ((v.u >> 16) & 1u)) >> 16;
  return (ushort)r;
}

// ---------------- cast fp32 -> bf16 (weight pre-pack) -----------------------
__global__ __launch_bounds__(256) void k_cast_bf16(
    const float* __restrict__ in, ushort* __restrict__ out, int n)
{
  int i = blockIdx.x * 256 + threadIdx.x;
  if (i < n) out[i] = f2bf(in[i]);
}

// ---------------- P1: POS q/k/v projection (stride-2 conv as GEMM) ----------
__global__ __launch_bounds__(256) void k_pos_qkv(
    const float* __restrict__ x,
    const float* __restrict__ Wq, const float* __restrict__ bq,
    const float* __restrict__ Wk, const float* __restrict__ bk,
    const float* __restrict__ Wv, const float* __restrict__ bv,
    float* __restrict__ Q, float* __restrict__ K, float* __restrict__ V)
{
  const int ot = blockIdx.x, lt = blockIdx.y, b = blockIdx.z;
  const int tid = threadIdx.x;
  __shared__ float At[64][68];
  __shared__ float Bt[64][68];
  const int l0 = lt * 64, o0 = ot * 64;
  int base; const float* Wsel; const float* bsel;
  if (ot == 0)      { base = 0;   Wsel = Wq; bsel = bq; }
  else if (ot == 1) { base = 64;  Wsel = Wk; bsel = bk; }
  else              { base = 128; Wsel = Wv; bsel = bv; }
  const int lj = (tid & 15) * 4, oi = (tid >> 4) * 4;
  float acc[4][4] = {};
  const float* xb = x + (size_t)b * 256 * 4096;
  for (int kc = 0; kc < 1024; kc += 64) {
    #pragma unroll
    for (int e0 = 0; e0 < 16; ++e0) {
      int e = e0 * 256 + tid;
      int kk = e >> 6, ll = e & 63;
      int k = kc + kk;
      int c = k >> 2, uv = k & 3;
      int l = l0 + ll;
      int y = 2 * (l >> 5) + (uv >> 1), xx = 2 * (l & 31) + (uv & 1);
      At[kk][ll] = xb[((size_t)c << 12) + (y << 6) + xx];
    }
    #pragma unroll
    for (int e0 = 0; e0 < 16; ++e0) {
      int e = e0 * 256 + tid;
      int oo = e >> 6, kk = e & 63;
      Bt[kk][oo] = Wsel[(size_t)(o0 - base + oo) * 1024 + kc + kk];
    }
    __syncthreads();
    #pragma unroll 16
    for (int kk = 0; kk < 64; ++kk) {
      float a[4], w[4];
      *(float4*)a = *(const float4*)&At[kk][lj];
      *(float4*)w = *(const float4*)&Bt[kk][oi];
      #pragma unroll
      for (int ii = 0; ii < 4; ++ii)
        #pragma unroll
        for (int jj = 0; jj < 4; ++jj)
          acc[ii][jj] += w[ii] * a[jj];
    }
    __syncthreads();
  }
  #pragma unroll
  for (int ii = 0; ii < 4; ++ii) {
    const int o = o0 + oi + ii;
    const float bias = bsel[o - base];
    #pragma unroll
    for (int jj = 0; jj < 4; ++jj) {
      const int l = l0 + lj + jj;
      const float val = acc[ii][jj] + bias;
      if (o < 64) {
        int hh = o >> 3, e = o & 7;
        Q[((((size_t)b * 8 + hh) << 10) + l) * 8 + e] = val;
      } else if (o < 128) {
        int o2 = o - 64, hh = o2 >> 3, e = o2 & 7;
        K[((((size_t)b * 8 + hh) << 10) + l) * 8 + e] = val;
      } else {
        int o2 = o - 128, hh = o2 >> 5, d = o2 & 31;
        V[((((size_t)b * 8 + hh) << 10) + l) * 32 + d] = val;
      }
    }
  }
}

// ---------------- P2: POS attention (two-pass, scores in LDS) ---------------
__global__ __launch_bounds__(256) void k_pos_attn(
    const float* __restrict__ Q, const float* __restrict__ K,
    const float* __restrict__ V, ushort* __restrict__ op)
{
  const int qt = blockIdx.x, h = blockIdx.y, b = blockIdx.z;
  __shared__ float sc[16][1024];
  __shared__ float qs[16][8];
  __shared__ float rinv[16];
  const int tid = threadIdx.x;
  const size_t bh = (size_t)b * 8 + h;
  const float* Qb = Q + bh * 8192;
  const float* Kb = K + bh * 8192;
  const float* Vb = V + bh * 32768;
  if (tid < 128) qs[tid >> 3][tid & 7] = Qb[(size_t)(qt * 16 + (tid >> 3)) * 8 + (tid & 7)];
  __syncthreads();
  const float scale = 0.35355339059327373f;  // 8^-0.5
  #pragma unroll 4
  for (int it = 0; it < 64; ++it) {
    int idx = it * 256 + tid;
    int r = idx >> 10, k = idx & 1023;
    float4 k0 = *(const float4*)(Kb + (size_t)k * 8);
    float4 k1 = *(const float4*)(Kb + (size_t)k * 8 + 4);
    float4 q0 = *(const float4*)&qs[r][0];
    float4 q1 = *(const float4*)&qs[r][4];
    float s = q0.x * k0.x + q0.y * k0.y + q0.z * k0.z + q0.w * k0.w
            + q1.x * k1.x + q1.y * k1.y + q1.z * k1.z + q1.w * k1.w;
    sc[r][k] = s * scale;
  }
  __syncthreads();
  {
    int r = tid >> 4, c0 = tid & 15;
    float m = -1e30f;
    for (int k = c0; k < 1024; k += 16) m = fmaxf(m, sc[r][k]);
    #pragma unroll
    for (int off = 8; off; off >>= 1) m = fmaxf(m, __shfl_xor(m, off, 16));
    float sum = 0.f;
    for (int k = c0; k < 1024; k += 16) { float p = __expf(sc[r][k] - m); sc[r][k] = p; sum += p; }
    #pragma unroll
    for (int off = 8; off; off >>= 1) sum += __shfl_xor(sum, off, 16);
    if (c0 == 0) rinv[r] = 1.f / sum;
  }
  __syncthreads();
  const int rr = tid >> 5, d = tid & 31;
  float acc0 = 0.f, acc1 = 0.f;
  #pragma unroll 4
  for (int k = 0; k < 1024; k += 4) {
    float4 p0 = *(const float4*)&sc[rr][k];
    float4 p1 = *(const float4*)&sc[rr + 8][k];
    float v0 = Vb[(size_t)(k + 0) * 32 + d];
    float v1 = Vb[(size_t)(k + 1) * 32 + d];
    float v2 = Vb[(size_t)(k + 2) * 32 + d];
    float v3 = Vb[(size_t)(k + 3) * 32 + d];
    acc0 += p0.x * v0 + p0.y * v1 + p0.z * v2 + p0.w * v3;
    acc1 += p1.x * v0 + p1.y * v1 + p1.z * v2 + p1.w * v3;
  }
  const int l1 = qt * 16 + rr, l2 = l1 + 8;
  const size_t ch = (size_t)b * 256 + h * 32 + d;
  op[ch * 1024 + l1] = f2bf(acc0 * rinv[rr]);
  op[ch * 1024 + l2] = f2bf(acc1 * rinv[rr + 8]);
}

// ------- 3x3 pad-1 conv, bf16 MFMA implicit GEMM (Wo conv & fusion conv) ----
template <int S, int CIN>
__global__ __launch_bounds__(256) void k_conv3x3_mfma(
    const ushort* __restrict__ in, const ushort* __restrict__ Wp,
    const float* __restrict__ bias, float* __restrict__ out)
{
  constexpr int K = CIN * 9;
  constexpr int NSP = S * S;
  const int n0 = blockIdx.x * 128, oc0 = blockIdx.y * 128, b = blockIdx.z;
  const int tid = threadIdx.x;
  const int lane = tid & 63, w = tid >> 6;
  __shared__ ushort As[128][32];
  __shared__ ushort Bs[128][40];
  const ushort* inb = in + (size_t)b * CIN * NSP;
  const int wr = w >> 1, wc = w & 1;
  f32x4 acc[4][4];
  #pragma unroll
  for (int mi = 0; mi < 4; ++mi)
    #pragma unroll
    for (int ni = 0; ni < 4; ++ni) {
      f32x4 z = {0.f, 0.f, 0.f, 0.f};
      acc[mi][ni] = z;
    }
  const int nloc = tid >> 1;
  const int n_g = n0 + nloc;
  const int yb = n_g / S, xb = n_g % S;
  const int kpart = (tid & 1) * 16;
  const char* wbase = (const char*)Wp;

  for (int kc = 0; kc < K; kc += 32) {
    __syncthreads();
    #pragma unroll
    for (int q = 0; q < 2; ++q) {
      int idx = w * 128 + q * 64 + lane;
      int ocr = idx >> 2, inner = (idx & 3) * 16;
      const char* src = wbase + ((size_t)(oc0 + ocr) * K + kc) * 2 + inner;
      char* dst = (char*)&As[0][0] + w * 2048 + q * 1024;
      __builtin_amdgcn_global_load_lds(
          (const __attribute__((address_space(1))) unsigned*)src,
          (__attribute__((address_space(3))) unsigned*)dst, 16, 0, 0);
    }
    union { uint4 q[2]; ushort s[16]; } vals;
    int k0 = kc + kpart;
    unsigned c = (unsigned)k0 / 9u;
    int t9 = k0 - (int)c * 9;
    #pragma unroll
    for (int j = 0; j < 16; ++j) {
      int t3 = (t9 >= 6) ? 2 : (t9 >= 3) ? 1 : 0;
      int dy = t3 - 1, dx = t9 - t3 * 3 - 1;
      int y = yb + dy, x = xb + dx;
      ushort v = 0;
      if ((unsigned)y < (unsigned)S && (unsigned)x < (unsigned)S)
        v = inb[(size_t)c * NSP + y * S + x];
      vals.s[j] = v;
      if (++t9 == 9) { t9 = 0; ++c; }
    }
    *(uint4*)&Bs[nloc][kpart] = vals.q[0];
    *(uint4*)&Bs[nloc][kpart + 8] = vals.q[1];
    __syncthreads();
    bf16x8 af[4], bfv[4];
    #pragma unroll
    for (int mi = 0; mi < 4; ++mi)
      af[mi] = *(const bf16x8*)&As[wr * 64 + mi * 16 + (lane & 15)][(lane >> 4) * 8];
    #pragma unroll
    for (int ni = 0; ni < 4; ++ni)
      bfv[ni] = *(const bf16x8*)&Bs[wc * 64 + ni * 16 + (lane & 15)][(lane >> 4) * 8];
    #pragma unroll
    for (int mi = 0; mi < 4; ++mi)
      #pragma unroll
      for (int ni = 0; ni < 4; ++ni)
        acc[mi][ni] = __builtin_amdgcn_mfma_f32_16x16x32_bf16(
            af[mi], bfv[ni], acc[mi][ni], 0, 0, 0);
  }
  float* outb = out + (size_t)b * 256 * NSP;
  #pragma unroll
  for (int mi = 0; mi < 4; ++mi) {
    #pragma unroll
    for (int r = 0; r < 4; ++r) {
      int oc = oc0 + wr * 64 + mi * 16 + (lane >> 4) * 4 + r;
      float bb = bias[oc];
      #pragma unroll
      for (int ni = 0; ni < 4; ++ni) {
        int n = n0 + wc * 64 + ni * 16 + (lane & 15);
        outb[(size_t)oc * NSP + n] = acc[mi][ni][r] + bb;
      }
    }
  }
}

// ---------------- P4: bilinear x2 upsample + residual -> fused[0:256] -------
__global__ __launch_bounds__(256) void k_upsample(
    const float* __restrict__ xpos, const float* __restrict__ opc,
    const float* __restrict__ gamma, ushort* __restrict__ fused)
{
  const int idx = blockIdx.x * 256 + threadIdx.x;
  const int xx = idx & 63, y = (idx >> 6) & 63, c = (idx >> 12) & 255, b = idx >> 20;
  const int my = y >> 1;
  const int y0 = (y & 1) ? my : my - 1;
  const float fy = (y & 1) ? 0.25f : 0.75f;
  const int mx = xx >> 1;
  const int x0 = (xx & 1) ? mx : mx - 1;
  const float fx = (xx & 1) ? 0.25f : 0.75f;
  const int y0c = max(y0, 0), y1c = min(y0 + 1, 31);
  const int x0c = max(x0, 0), x1c = min(x0 + 1, 31);
  const float* Pc = opc + ((size_t)b * 256 + c) * 1024;
  const float v00 = Pc[y0c * 32 + x0c], v01 = Pc[y0c * 32 + x1c];
  const float v10 = Pc[y1c * 32 + x0c], v11 = Pc[y1c * 32 + x1c];
  const float v = (1.f - fy) * ((1.f - fx) * v00 + fx * v01)
                + fy * ((1.f - fx) * v10 + fx * v11);
  fused[(size_t)idx + (size_t)b * 256 * 4096] = f2bf(xpos[idx] + gamma[0] * v);
}

// ------- C0: CHA q/k/v grouped 2x2 projections -> bf16 (half-batch) ---------
// qc: [bhl][c2][l] (scaled by L^-0.5), kc: [bhl][c2][l], vcT: [bhl][l][d]
__global__ __launch_bounds__(256) void k_cha_proj(
    const float* __restrict__ x,   // already offset to this half's first b
    const float* __restrict__ Wq, const float* __restrict__ bq,
    const float* __restrict__ Wk, const float* __restrict__ bk,
    const float* __restrict__ Wv, const float* __restrict__ bv,
    ushort* __restrict__ Qc, ushort* __restrict__ Kc, ushort* __restrict__ Vt)
{
  const int t = blockIdx.x * 256 + threadIdx.x;   // 262144 threads
  const int bl = t >> 16;
  const int g  = (t >> 8) & 255;   // block-uniform
  const int lq = t & 255;
  const int i = lq >> 3, j4 = (lq & 7) << 2;
  const float* xb = x + (((size_t)bl * 256 + g) << 12) + (2 * i) * 64 + 2 * j4;
  union { float4 v[2]; float f[8]; } xr0, xr1;
  xr0.v[0] = *(const float4*)(xb);
  xr0.v[1] = *(const float4*)(xb + 4);
  xr1.v[0] = *(const float4*)(xb + 64);
  xr1.v[1] = *(const float4*)(xb + 68);
  const int bhl = bl * 8 + (g >> 5);
  const int c2b = (g & 31) * 8;
  const int l0 = i * 32 + j4;
  // q projection (scale folded)
  #pragma unroll
  for (int h = 0; h < 8; ++h) {
    float4 w4 = *(const float4*)(Wq + g * 32 + h * 4);
    float bb = bq[g * 8 + h];
    union { ushort u[4]; uint2 q; } o;
    #pragma unroll
    for (int jj = 0; jj < 4; ++jj) {
      float v = xr0.f[2 * jj] * w4.x + xr0.f[2 * jj + 1] * w4.y
              + xr1.f[2 * jj] * w4.z + xr1.f[2 * jj + 1] * w4.w + bb;
      o.u[jj] = f2bf(v * 0.03125f);
    }
    *(uint2*)(Qc + (((size_t)bhl * 256 + c2b + h) << 10) + l0) = o.q;
  }
  // k projection
  #pragma unroll
  for (int h = 0; h < 8; ++h) {
    float4 w4 = *(const float4*)(Wk + g * 32 + h * 4);
    float bb = bk[g * 8 + h];
    union { ushort u[4]; uint2 q; } o;
    #pragma unroll
    for (int jj = 0; jj < 4; ++jj) {
      float v = xr0.f[2 * jj] * w4.x + xr0.f[2 * jj + 1] * w4.y
              + xr1.f[2 * jj] * w4.z + xr1.f[2 * jj + 1] * w4.w + bb;
      o.u[jj] = f2bf(v);
    }
    *(uint2*)(Kc + (((size_t)bhl * 256 + c2b + h) << 10) + l0) = o.q;
  }
  // v projection, transposed store [l][d]
  ushort vo[4][8];
  #pragma unroll
  for (int h = 0; h < 8; ++h) {
    float4 w4 = *(const float4*)(Wv + g * 32 + h * 4);
    float bb = bv[g * 8 + h];
    #pragma unroll
    for (int jj = 0; jj < 4; ++jj) {
      float v = xr0.f[2 * jj] * w4.x + xr0.f[2 * jj + 1] * w4.y
              + xr1.f[2 * jj] * w4.z + xr1.f[2 * jj + 1] * w4.w + bb;
      vo[jj][h] = f2bf(v);
    }
  }
  #pragma unroll
  for (int jj = 0; jj < 4; ++jj)
    *(uint4*)(Vt + ((size_t)bhl << 18) + (size_t)(l0 + jj) * 256 + c2b) =
        *(uint4*)&vo[jj][0];
}

// ------- C1: scores = qc @ kc^T, bf16 MFMA, K=1024 (half-batch) -------------
__global__ __launch_bounds__(256) void k_cha_scores_mfma(
    const ushort* __restrict__ Qc, const ushort* __restrict__ Kc,
    float* __restrict__ S)
{
  const int c0 = blockIdx.x * 128, d0 = blockIdx.y * 128, bhl = blockIdx.z;
  const int tid = threadIdx.x, lane = tid & 63, w = tid >> 6;
  __shared__ ushort As[128][32], Bs[128][32];
  const ushort* Ab = Qc + ((size_t)bhl * 256 + c0) * 1024;
  const ushort* Bb = Kc + ((size_t)bhl * 256 + d0) * 1024;
  const int wr = w >> 1, wc = w & 1;
  f32x4 acc[4][4];
  #pragma unroll
  for (int mi = 0; mi < 4; ++mi)
    #pragma unroll
    for (int ni = 0; ni < 4; ++ni) {
      f32x4 z = {0.f, 0.f, 0.f, 0.f};
      acc[mi][ni] = z;
    }
  for (int kc = 0; kc < 1024; kc += 32) {
    __syncthreads();
    #pragma unroll
    for (int q = 0; q < 2; ++q) {
      int idx = w * 128 + q * 64 + lane;
      int row = idx >> 2, seg = idx & 3;
      const ushort* srcA = Ab + (size_t)row * 1024 + kc + seg * 8;
      const ushort* srcB = Bb + (size_t)row * 1024 + kc + seg * 8;
      char* dstA = (char*)&As[0][0] + w * 2048 + q * 1024;
      char* dstB = (char*)&Bs[0][0] + w * 2048 + q * 1024;
      __builtin_amdgcn_global_load_lds(
          (const __attribute__((address_space(1))) unsigned*)srcA,
          (__attribute__((address_space(3))) unsigned*)dstA, 16, 0, 0);
      __builtin_amdgcn_global_load_lds(
          (const __attribute__((address_space(1))) unsigned*)srcB,
          (__attribute__((address_space(3))) unsigned*)dstB, 16, 0, 0);
    }
    __syncthreads();
    bf16x8 af[4], bfv[4];
    #pragma unroll
    for (int mi = 0; mi < 4; ++mi)
      af[mi] = *(const bf16x8*)&As[wr * 64 + mi * 16 + (lane & 15)][(lane >> 4) * 8];
    #pragma unroll
    for (int ni = 0; ni < 4; ++ni)
      bfv[ni] = *(const bf16x8*)&Bs[wc * 64 + ni * 16 + (lane & 15)][(lane >> 4) * 8];
    #pragma unroll
    for (int mi = 0; mi < 4; ++mi)
      #pragma unroll
      for (int ni = 0; ni < 4; ++ni)
        acc[mi][ni] = __builtin_amdgcn_mfma_f32_16x16x32_bf16(
            af[mi], bfv[ni], acc[mi][ni], 0, 0, 0);
  }
  float* Sb = S + ((size_t)bhl << 16);
  #pragma unroll
  for (int mi = 0; mi < 4; ++mi)
    #pragma unroll
    for (int r = 0; r < 4; ++r) {
      int c = c0 + wr * 64 + mi * 16 + (lane >> 4) * 4 + r;
      #pragma unroll
      for (int ni = 0; ni < 4; ++ni) {
        int d = d0 + wc * 64 + ni * 16 + (lane & 15);
        Sb[(size_t)c * 256 + d] = acc[mi][ni][r];
      }
    }
}

// ------- C2: row softmax over 256 -> bf16 P ---------------------------------
__global__ __launch_bounds__(256) void k_softmax_p(
    const float* __restrict__ S, ushort* __restrict__ P)
{
  const int row = blockIdx.x * 4 + (threadIdx.x >> 6);
  const int lane = threadIdx.x & 63;
  const float* r = S + (size_t)row * 256;
  float4 v = *(const float4*)(r + lane * 4);
  float m = fmaxf(fmaxf(v.x, v.y), fmaxf(v.z, v.w));
  #pragma unroll
  for (int off = 32; off; off >>= 1) m = fmaxf(m, __shfl_xor(m, off, 64));
  v.x = __expf(v.x - m); v.y = __expf(v.y - m);
  v.z = __expf(v.z - m); v.w = __expf(v.w - m);
  float s = v.x + v.y + v.z + v.w;
  #pragma unroll
  for (int off = 32; off; off >>= 1) s += __shfl_xor(s, off, 64);
  const float inv = 1.f / s;
  union { ushort u[4]; uint2 q; } o;
  o.u[0] = f2bf(v.x * inv); o.u[1] = f2bf(v.y * inv);
  o.u[2] = f2bf(v.z * inv); o.u[3] = f2bf(v.w * inv);
  *(uint2*)(P + (size_t)row * 256 + lane * 4) = o.q;
}

// ------- C3: oc = P @ vcT (MFMA, K=256) + grouped ConvT + residual ----------
__global__ __launch_bounds__(256) void k_cha_pv(
    const ushort* __restrict__ P, const ushort* __restrict__ Vt,
    const float* __restrict__ x,   // full qkv_cha
    const float* __restrict__ Wt, const float* __restrict__ bt,
    const float* __restrict__ gamma, ushort* __restrict__ fused, int bbase)
{
  const int n0 = blockIdx.x * 128, c0 = blockIdx.y * 128, bhl = blockIdx.z;
  const int b = bbase + (bhl >> 3), h = bhl & 7;
  const int tid = threadIdx.x, lane = tid & 63, w = tid >> 6;
  __shared__ ushort As[128][32], Bs[128][32];
  __shared__ float wt_s[16][32];
  __shared__ float bt_s[16];
  const int gp_base = h * 32 + (c0 >> 3);
  // load ConvT weights for this block's 16 output channels
  {
    int e = tid;
    wt_s[e >> 5][e & 31] = Wt[(size_t)gp_base * 32 + e];
    e += 256;
    wt_s[e >> 5][e & 31] = Wt[(size_t)gp_base * 32 + e];
    if (tid < 16) bt_s[tid] = bt[gp_base + tid];
  }
  const ushort* Ab = P + (((size_t)bhl << 8) + c0) * 256;
  const ushort* Bb = Vt + ((size_t)bhl << 18) + (size_t)n0 * 256;
  const int wr = w >> 1, wc = w & 1;
  f32x4 acc[4][4];
  #pragma unroll
  for (int mi = 0; mi < 4; ++mi)
    #pragma unroll
    for (int ni = 0; ni < 4; ++ni) {
      f32x4 z = {0.f, 0.f, 0.f, 0.f};
      acc[mi][ni] = z;
    }
  for (int kc = 0; kc < 256; kc += 32) {
    __syncthreads();
    #pragma unroll
    for (int q = 0; q < 2; ++q) {
      int idx = w * 128 + q * 64 + lane;
      int row = idx >> 2, seg = idx & 3;
      const ushort* srcA = Ab + (size_t)row * 256 + kc + seg * 8;
      const ushort* srcB = Bb + (size_t)row * 256 + kc + seg * 8;
      char* dstA = (char*)&As[0][0] + w * 2048 + q * 1024;
      char* dstB = (char*)&Bs[0][0] + w * 2048 + q * 1024;
      __builtin_amdgcn_global_load_lds(
          (const __attribute__((address_space(1))) unsigned*)srcA,
          (__attribute__((address_space(3))) unsigned*)dstA, 16, 0, 0);
      __builtin_amdgcn_global_load_lds(
          (const __attribute__((address_space(1))) unsigned*)srcB,
          (__attribute__((address_space(3))) unsigned*)dstB, 16, 0, 0);
    }
    __syncthreads();
    bf16x8 af[4], bfv[4];
    #pragma unroll
    for (int mi = 0; mi < 4; ++mi)
      af[mi] = *(const bf16x8*)&As[wr * 64 + mi * 16 + (lane & 15)][(lane >> 4) * 8];
    #pragma unroll
    for (int ni = 0; ni < 4; ++ni)
      bfv[ni] = *(const bf16x8*)&Bs[wc * 64 + ni * 16 + (lane & 15)][(lane >> 4) * 8];
    #pragma unroll
    for (int mi = 0; mi < 4; ++mi)
      #pragma unroll
      for (int ni = 0; ni < 4; ++ni)
        acc[mi][ni] = __builtin_amdgcn_mfma_f32_16x16x32_bf16(
            af[mi], bfv[ni], acc[mi][ni], 0, 0, 0);
  }
  // epilogue: grouped ConvTranspose2d (k=s=2) over 8-row groups + residual
  const float gm = gamma[0];
  const int col = lane & 15, q = lane >> 4;
  #pragma unroll
  for (int mi = 0; mi < 4; ++mi) {
    const int gloc = wr * 8 + mi * 2 + (q >> 1);
    const int gp = gp_base + gloc;
    const float btv = bt_s[gloc];
    #pragma unroll
    for (int ni = 0; ni < 4; ++ni) {
      float pa[4] = {0.f, 0.f, 0.f, 0.f};
      #pragma unroll
      for (int r = 0; r < 4; ++r) {
        const int i2 = (q & 1) * 4 + r;
        const float a = acc[mi][ni][r];
        pa[0] += a * wt_s[gloc][i2 * 4 + 0];
        pa[1] += a * wt_s[gloc][i2 * 4 + 1];
        pa[2] += a * wt_s[gloc][i2 * 4 + 2];
        pa[3] += a * wt_s[gloc][i2 * 4 + 3];
      }
      float v0 = pa[0] + __shfl_xor(pa[0], 16, 64);
      float v1 = pa[1] + __shfl_xor(pa[1], 16, 64);
      float v2 = pa[2] + __shfl_xor(pa[2], 16, 64);
      float v3 = pa[3] + __shfl_xor(pa[3], 16, 64);
      const int l = n0 + wc * 64 + ni * 16 + col;
      const int p = l >> 5, j = l & 31;
      const int y = 2 * p + (q & 1);
      const float va = (q & 1) ? v2 : v0;
      const float vb = (q & 1) ? v3 : v1;
      const float* xc = x + (((size_t)b * 256 + gp) << 12) + (y << 6) + 2 * j;
      union { ushort u[2]; unsigned uu; } o;
      o.u[0] = f2bf(xc[0] + gm * (va + btv));
      o.u[1] = f2bf(xc[1] + gm * (vb + btv));
      *(unsigned*)(fused + (((size_t)b * 512 + 256 + gp) << 12) + (y << 6) + 2 * j) = o.uu;
    }
  }
}

extern "C" void kernel_launch(void* const* d_in, const int* in_sizes, int n_in,
                              void* d_out, int out_size, void* d_ws, size_t ws_size,
                              hipStream_t stream)
{
  (void)in_sizes; (void)n_in; (void)out_size; (void)ws_size;
  const float* qkv_pos   = (const float*)d_in[0];
  const float* qkv_cha   = (const float*)d_in[1];
  const float* Wq_pos    = (const float*)d_in[2];
  const float* bq_pos    = (const float*)d_in[3];
  const float* Wk_pos    = (const float*)d_in[4];
  const float* bk_pos    = (const float*)d_in[5];
  const float* Wv_pos    = (const float*)d_in[6];
  const float* bv_pos    = (const float*)d_in[7];
  const float* Wo_pos    = (const float*)d_in[8];
  const float* bo_pos    = (const float*)d_in[9];
  const float* gamma_pos = (const float*)d_in[10];
  const float* Wq_cha    = (const float*)d_in[11];
  const float* bq_cha    = (const float*)d_in[12];
  const float* Wk_cha    = (const float*)d_in[13];
  const float* bk_cha    = (const float*)d_in[14];
  const float* Wv_cha    = (const float*)d_in[15];
  const float* bv_cha    = (const float*)d_in[16];
  const float* Wt_cha    = (const float*)d_in[17];
  const float* bt_cha    = (const float*)d_in[18];
  const float* gamma_cha = (const float*)d_in[19];
  const float* Wf        = (const float*)d_in[20];
  const float* bf        = (const float*)d_in[21];
  float* out = (float*)d_out;

  float* ws = (float*)d_ws;
  ushort* Wpf     = (ushort*)ws;
  ushort* Wpo     = (ushort*)(ws + 589824);
  // POS scratch (region2)
  float*  Qp      = ws + 884736;
  float*  Kp      = Qp + 524288;
  float*  Vp      = Kp + 524288;
  ushort* op_attn = (ushort*)(Vp + 2097152);
  float*  op_conv = ws + 5079040;
  // CHA scratch (aliases region2, used after POS completes)
  ushort* qcb     = (ushort*)(ws + 884736);
  ushort* kcb     = (ushort*)(ws + 5079040);
  ushort* vcT     = (ushort*)(ws + 9273344);
  float*  attn_c  = ws + 13467648;
  ushort* Pb      = (ushort*)(ws + 15564800);
  ushort* fusedb  = (ushort*)(ws + 16613376);

  // weight pre-pack (bf16)
  k_cast_bf16<<<dim3(4608), 256, 0, stream>>>(Wf, Wpf, 1179648);
  k_cast_bf16<<<dim3(2304), 256, 0, stream>>>(Wo_pos, Wpo, 589824);
  // POS branch (uses POS scratch; completes before CHA aliases it)
  k_pos_qkv<<<dim3(6, 16, 8), 256, 0, stream>>>(qkv_pos, Wq_pos, bq_pos,
      Wk_pos, bk_pos, Wv_pos, bv_pos, Qp, Kp, Vp);
  k_pos_attn<<<dim3(64, 8, 8), 256, 0, stream>>>(Qp, Kp, Vp, op_attn);
  k_conv3x3_mfma<32, 256><<<dim3(8, 2, 8), 256, 0, stream>>>(op_attn, Wpo, bo_pos, op_conv);
  k_upsample<<<dim3(32768), 256, 0, stream>>>(qkv_pos, op_conv, gamma_pos, fusedb);
  // CHA branch, two half-batches (b 0..3, 4..7) to bound workspace
  for (int half = 0; half < 2; ++half) {
    const float* xh = qkv_cha + (size_t)half * 4 * 256 * 4096;
    k_cha_proj<<<dim3(1024), 256, 0, stream>>>(xh, Wq_cha, bq_cha,
        Wk_cha, bk_cha, Wv_cha, bv_cha, qcb, kcb, vcT);
    k_cha_scores_mfma<<<dim3(2, 2, 32), 256, 0, stream>>>(qcb, kcb, attn_c);
    k_softmax_p<<<dim3(2048), 256, 0, stream>>>(attn_c, Pb);
    k_cha_pv<<<dim3(8, 2, 32), 256, 0, stream>>>(Pb, vcT, qkv_cha,
        Wt_cha, bt_cha, gamma_cha, fusedb, half * 4);
  }
  // fusion conv (bf16 MFMA)
  k_conv3x3_mfma<64, 512><<<dim3(32, 2, 8), 256, 0, stream>>>(fusedb, Wpf, bf, out);
}

// Round 4
// 978.071 us; speedup vs baseline: 2.8969x; 1.1853x over previous
//
#include <hip/hip_runtime.h>
#include <math.h>

// Shapes: B=8, C=256, H=W=64, HQ=WQ=32, L=1024, NH=8, hd=8, dv=32
//
// Workspace (float units), total 25,534,464 f ~= 102 MB:
//   Wpf9 bf16[9][256][512] @ 0        (589824 f)
//   Wpo9 bf16[9][256][256] @ 589824   (294912 f)
//   region2 @ 884736 (POS scratch, later aliased by CHA scratch):
//     POS: Qp @884736 (524288) | Kp @1409024 (524288) | Vp @1933312 (2097152)
//          op_pad bf16[8][34*34][256] @4030464 (1183744 f)
//          op_conv f32 NHWC [8][1024][256] @5214208 (2097152 f)
//     CHA: qcb bf16 @884736 | kcb @5079040 | vcT @9273344 (4194304 f each)
//          attn_c f32 @13467648 (2097152) | P bf16 @15564800 (1048576 f)
//   fused_pad bf16[8][66*66][512] @ 16613376 (8921088 f)

typedef __attribute__((ext_vector_type(8))) short bf16x8;
typedef __attribute__((ext_vector_type(4))) float f32x4;

__device__ __forceinline__ ushort f2bf(float f) {
  union { float f; unsigned u; } v; v.f = f;
  unsigned r = (v.u + 0x7FFFu + ((v.u >> 16) & 1u)) >> 16;
  return (ushort)r;
}

// -------- weight pre-pack: W[oc][cin][3][3] fp32 -> [t][oc][cin] bf16 -------
template <int CIN>
__global__ __launch_bounds__(256) void k_prepack9(
    const float* __restrict__ W, ushort* __restrict__ out)
{
  const int i = blockIdx.x * 256 + threadIdx.x;   // over 9*256*CIN
  const int t = i / (256 * CIN);
  const int r = i - t * (256 * CIN);
  const int oc = r / CIN;
  const int c = r - oc * CIN;
  out[i] = f2bf(W[((size_t)oc * CIN + c) * 9 + t]);
}

// ---------------- P1: POS q/k/v projection (stride-2 conv as GEMM) ----------
__global__ __launch_bounds__(256) void k_pos_qkv(
    const float* __restrict__ x,
    const float* __restrict__ Wq, const float* __restrict__ bq,
    const float* __restrict__ Wk, const float* __restrict__ bk,
    const float* __restrict__ Wv, const float* __restrict__ bv,
    float* __restrict__ Q, float* __restrict__ K, float* __restrict__ V)
{
  const int ot = blockIdx.x, lt = blockIdx.y, b = blockIdx.z;
  const int tid = threadIdx.x;
  __shared__ float At[64][68];
  __shared__ float Bt[64][68];
  const int l0 = lt * 64, o0 = ot * 64;
  int base; const float* Wsel; const float* bsel;
  if (ot == 0)      { base = 0;   Wsel = Wq; bsel = bq; }
  else if (ot == 1) { base = 64;  Wsel = Wk; bsel = bk; }
  else              { base = 128; Wsel = Wv; bsel = bv; }
  const int lj = (tid & 15) * 4, oi = (tid >> 4) * 4;
  float acc[4][4] = {};
  const float* xb = x + (size_t)b * 256 * 4096;
  for (int kc = 0; kc < 1024; kc += 64) {
    #pragma unroll
    for (int e0 = 0; e0 < 16; ++e0) {
      int e = e0 * 256 + tid;
      int kk = e >> 6, ll = e & 63;
      int k = kc + kk;
      int c = k >> 2, uv = k & 3;
      int l = l0 + ll;
      int y = 2 * (l >> 5) + (uv >> 1), xx = 2 * (l & 31) + (uv & 1);
      At[kk][ll] = xb[((size_t)c << 12) + (y << 6) + xx];
    }
    #pragma unroll
    for (int e0 = 0; e0 < 16; ++e0) {
      int e = e0 * 256 + tid;
      int oo = e >> 6, kk = e & 63;
      Bt[kk][oo] = Wsel[(size_t)(o0 - base + oo) * 1024 + kc + kk];
    }
    __syncthreads();
    #pragma unroll 16
    for (int kk = 0; kk < 64; ++kk) {
      float a[4], w[4];
      *(float4*)a = *(const float4*)&At[kk][lj];
      *(float4*)w = *(const float4*)&Bt[kk][oi];
      #pragma unroll
      for (int ii = 0; ii < 4; ++ii)
        #pragma unroll
        for (int jj = 0; jj < 4; ++jj)
          acc[ii][jj] += w[ii] * a[jj];
    }
    __syncthreads();
  }
  #pragma unroll
  for (int ii = 0; ii < 4; ++ii) {
    const int o = o0 + oi + ii;
    const float bias = bsel[o - base];
    #pragma unroll
    for (int jj = 0; jj < 4; ++jj) {
      const int l = l0 + lj + jj;
      const float val = acc[ii][jj] + bias;
      if (o < 64) {
        int hh = o >> 3, e = o & 7;
        Q[((((size_t)b * 8 + hh) << 10) + l) * 8 + e] = val;
      } else if (o < 128) {
        int o2 = o - 64, hh = o2 >> 3, e = o2 & 7;
        K[((((size_t)b * 8 + hh) << 10) + l) * 8 + e] = val;
      } else {
        int o2 = o - 128, hh = o2 >> 5, d = o2 & 31;
        V[((((size_t)b * 8 + hh) << 10) + l) * 32 + d] = val;
      }
    }
  }
}

// ------ P2: POS attention -> op_pad NHWC padded bf16 [b][34*34][256] --------
__global__ __launch_bounds__(256) void k_pos_attn(
    const float* __restrict__ Q, const float* __restrict__ K,
    const float* __restrict__ V, ushort* __restrict__ op_pad)
{
  const int qt = blockIdx.x, h = blockIdx.y, b = blockIdx.z;
  __shared__ float sc[16][1024];
  __shared__ float qs[16][8];
  __shared__ float rinv[16];
  const int tid = threadIdx.x;
  const size_t bh = (size_t)b * 8 + h;
  const float* Qb = Q + bh * 8192;
  const float* Kb = K + bh * 8192;
  const float* Vb = V + bh * 32768;
  if (tid < 128) qs[tid >> 3][tid & 7] = Qb[(size_t)(qt * 16 + (tid >> 3)) * 8 + (tid & 7)];
  __syncthreads();
  const float scale = 0.35355339059327373f;  // 8^-0.5
  #pragma unroll 4
  for (int it = 0; it < 64; ++it) {
    int idx = it * 256 + tid;
    int r = idx >> 10, k = idx & 1023;
    float4 k0 = *(const float4*)(Kb + (size_t)k * 8);
    float4 k1 = *(const float4*)(Kb + (size_t)k * 8 + 4);
    float4 q0 = *(const float4*)&qs[r][0];
    float4 q1 = *(const float4*)&qs[r][4];
    float s = q0.x * k0.x + q0.y * k0.y + q0.z * k0.z + q0.w * k0.w
            + q1.x * k1.x + q1.y * k1.y + q1.z * k1.z + q1.w * k1.w;
    sc[r][k] = s * scale;
  }
  __syncthreads();
  {
    int r = tid >> 4, c0 = tid & 15;
    float m = -1e30f;
    for (int k = c0; k < 1024; k += 16) m = fmaxf(m, sc[r][k]);
    #pragma unroll
    for (int off = 8; off; off >>= 1) m = fmaxf(m, __shfl_xor(m, off, 16));
    float sum = 0.f;
    for (int k = c0; k < 1024; k += 16) { float p = __expf(sc[r][k] - m); sc[r][k] = p; sum += p; }
    #pragma unroll
    for (int off = 8; off; off >>= 1) sum += __shfl_xor(sum, off, 16);
    if (c0 == 0) rinv[r] = 1.f / sum;
  }
  __syncthreads();
  const int rr = tid >> 5, d = tid & 31;
  float acc0 = 0.f, acc1 = 0.f;
  #pragma unroll 4
  for (int k = 0; k < 1024; k += 4) {
    float4 p0 = *(const float4*)&sc[rr][k];
    float4 p1 = *(const float4*)&sc[rr + 8][k];
    float v0 = Vb[(size_t)(k + 0) * 32 + d];
    float v1 = Vb[(size_t)(k + 1) * 32 + d];
    float v2 = Vb[(size_t)(k + 2) * 32 + d];
    float v3 = Vb[(size_t)(k + 3) * 32 + d];
    acc0 += p0.x * v0 + p0.y * v1 + p0.z * v2 + p0.w * v3;
    acc1 += p1.x * v0 + p1.y * v1 + p1.z * v2 + p1.w * v3;
  }
  const int l1 = qt * 16 + rr, l2 = l1 + 8;
  const int ch = h * 32 + d;
  const int y1 = l1 >> 5, x1 = l1 & 31;
  const int y2 = l2 >> 5, x2 = l2 & 31;
  op_pad[((size_t)b * 1156 + (y1 + 1) * 34 + (x1 + 1)) * 256 + ch] = f2bf(acc0 * rinv[rr]);
  op_pad[((size_t)b * 1156 + (y2 + 1) * 34 + (x2 + 1)) * 256 + ch] = f2bf(acc1 * rinv[rr + 8]);
}

// ------ 3x3 conv as 9 shifted GEMMs over padded NHWC, bf16 MFMA -------------
// in: bf16 NHWC padded [b][PW*PW][CIN] (border zero); W9: bf16 [9][256][CIN];
// OUT_NHWC=1 -> fp32 [b][S*S][256];  OUT_NHWC=0 -> fp32 NCHW [b][256][S*S]
template <int CIN, int S, int PW, int OUT_NHWC>
__global__ __launch_bounds__(256) void k_conv9_mfma(
    const ushort* __restrict__ in, const ushort* __restrict__ W9,
    const float* __restrict__ bias, float* __restrict__ out)
{
  const int n0 = blockIdx.x * 128, oc0 = blockIdx.y * 128, b = blockIdx.z;
  const int tid = threadIdx.x, lane = tid & 63, w = tid >> 6;
  __shared__ ushort As[128][32], Bs[128][32];
  const int wr = w >> 1, wc = w & 1;
  f32x4 acc[4][4];
  #pragma unroll
  for (int mi = 0; mi < 4; ++mi)
    #pragma unroll
    for (int ni = 0; ni < 4; ++ni) {
      f32x4 z = {0.f, 0.f, 0.f, 0.f};
      acc[mi][ni] = z;
    }
  // per-lane, per-q staging geometry
  int rowq[2], segq[2], basep[2];
  #pragma unroll
  for (int q = 0; q < 2; ++q) {
    int idx = w * 128 + q * 64 + lane;
    rowq[q] = idx >> 2;
    segq[q] = (idx & 3) * 8;   // ushort offset within row
    int n = n0 + rowq[q];
    int y = n / S, x = n % S;  // S is power of two -> shifts
    basep[q] = y * PW + x;
  }
  const ushort* inb = in + (size_t)b * (PW * PW) * CIN;

  for (int t = 0; t < 9; ++t) {
    const int offp = (t / 3) * PW + (t % 3);
    const ushort* wt = W9 + (size_t)t * 256 * CIN;
    for (int kc = 0; kc < CIN; kc += 32) {
      __syncthreads();
      #pragma unroll
      for (int q = 0; q < 2; ++q) {
        const ushort* srcA = wt + (size_t)(oc0 + rowq[q]) * CIN + kc + segq[q];
        const ushort* srcB = inb + (size_t)(basep[q] + offp) * CIN + kc + segq[q];
        char* dstA = (char*)&As[0][0] + w * 2048 + q * 1024;
        char* dstB = (char*)&Bs[0][0] + w * 2048 + q * 1024;
        __builtin_amdgcn_global_load_lds(
            (const __attribute__((address_space(1))) unsigned*)srcA,
            (__attribute__((address_space(3))) unsigned*)dstA, 16, 0, 0);
        __builtin_amdgcn_global_load_lds(
            (const __attribute__((address_space(1))) unsigned*)srcB,
            (__attribute__((address_space(3))) unsigned*)dstB, 16, 0, 0);
      }
      __syncthreads();
      bf16x8 af[4], bfv[4];
      #pragma unroll
      for (int mi = 0; mi < 4; ++mi)
        af[mi] = *(const bf16x8*)&As[wr * 64 + mi * 16 + (lane & 15)][(lane >> 4) * 8];
      #pragma unroll
      for (int ni = 0; ni < 4; ++ni)
        bfv[ni] = *(const bf16x8*)&Bs[wc * 64 + ni * 16 + (lane & 15)][(lane >> 4) * 8];
      #pragma unroll
      for (int mi = 0; mi < 4; ++mi)
        #pragma unroll
        for (int ni = 0; ni < 4; ++ni)
          acc[mi][ni] = __builtin_amdgcn_mfma_f32_16x16x32_bf16(
              af[mi], bfv[ni], acc[mi][ni], 0, 0, 0);
    }
  }
  if (OUT_NHWC) {
    float* outb = out + (size_t)b * (S * S) * 256;
    #pragma unroll
    for (int mi = 0; mi < 4; ++mi) {
      const int oc = oc0 + wr * 64 + mi * 16 + (lane >> 4) * 4;
      float4 bb = *(const float4*)(bias + oc);
      #pragma unroll
      for (int ni = 0; ni < 4; ++ni) {
        const int n = n0 + wc * 64 + ni * 16 + (lane & 15);
        float4 v;
        v.x = acc[mi][ni][0] + bb.x;
        v.y = acc[mi][ni][1] + bb.y;
        v.z = acc[mi][ni][2] + bb.z;
        v.w = acc[mi][ni][3] + bb.w;
        *(float4*)(outb + (size_t)n * 256 + oc) = v;
      }
    }
  } else {
    float* outb = out + (size_t)b * 256 * (S * S);
    #pragma unroll
    for (int mi = 0; mi < 4; ++mi) {
      #pragma unroll
      for (int r = 0; r < 4; ++r) {
        int oc = oc0 + wr * 64 + mi * 16 + (lane >> 4) * 4 + r;
        float bb = bias[oc];
        #pragma unroll
        for (int ni = 0; ni < 4; ++ni) {
          int n = n0 + wc * 64 + ni * 16 + (lane & 15);
          outb[(size_t)oc * (S * S) + n] = acc[mi][ni][r] + bb;
        }
      }
    }
  }
}

// ---- P4: bilinear x2 upsample + residual -> fused_pad[.., ch 0:256] --------
// opc: fp32 NHWC [b][1024][256]; xpos: fp32 NCHW; out: bf16 NHWC padded
__global__ __launch_bounds__(256) void k_upsample_nhwc(
    const float* __restrict__ xpos, const float* __restrict__ opc,
    const float* __restrict__ gamma, ushort* __restrict__ fused)
{
  const int t = blockIdx.x * 256 + threadIdx.x;  // 8*4096*64
  const int c = (t & 63) * 4;
  const int pix = (t >> 6) & 4095;
  const int b = t >> 18;
  const int y = pix >> 6, xx = pix & 63;
  const int my = y >> 1;
  const int y0 = (y & 1) ? my : my - 1;
  const float fy = (y & 1) ? 0.25f : 0.75f;
  const int mx = xx >> 1;
  const int x0 = (xx & 1) ? mx : mx - 1;
  const float fx = (xx & 1) ? 0.25f : 0.75f;
  const int y0c = max(y0, 0), y1c = min(y0 + 1, 31);
  const int x0c = max(x0, 0), x1c = min(x0 + 1, 31);
  const float* base = opc + (size_t)b * 1024 * 256 + c;
  float4 v00 = *(const float4*)(base + (size_t)(y0c * 32 + x0c) * 256);
  float4 v01 = *(const float4*)(base + (size_t)(y0c * 32 + x1c) * 256);
  float4 v10 = *(const float4*)(base + (size_t)(y1c * 32 + x0c) * 256);
  float4 v11 = *(const float4*)(base + (size_t)(y1c * 32 + x1c) * 256);
  const float w00 = (1.f - fy) * (1.f - fx), w01 = (1.f - fy) * fx;
  const float w10 = fy * (1.f - fx), w11 = fy * fx;
  const float g = gamma[0];
  const float* xr = xpos + ((size_t)b * 256 + c) * 4096 + pix;
  union { ushort u[4]; uint2 q; } o;
  o.u[0] = f2bf(xr[0]          + g * (w00 * v00.x + w01 * v01.x + w10 * v10.x + w11 * v11.x));
  o.u[1] = f2bf(xr[4096]       + g * (w00 * v00.y + w01 * v01.y + w10 * v10.y + w11 * v11.y));
  o.u[2] = f2bf(xr[2 * 4096]   + g * (w00 * v00.z + w01 * v01.z + w10 * v10.z + w11 * v11.z));
  o.u[3] = f2bf(xr[3 * 4096]   + g * (w00 * v00.w + w01 * v01.w + w10 * v10.w + w11 * v11.w));
  *(uint2*)(fused + ((size_t)b * 4356 + (y + 1) * 66 + (xx + 1)) * 512 + c) = o.q;
}

// ------- C0: CHA q/k/v grouped 2x2 projections -> bf16 (half-batch) ---------
__global__ __launch_bounds__(256) void k_cha_proj(
    const float* __restrict__ x,
    const float* __restrict__ Wq, const float* __restrict__ bq,
    const float* __restrict__ Wk, const float* __restrict__ bk,
    const float* __restrict__ Wv, const float* __restrict__ bv,
    ushort* __restrict__ Qc, ushort* __restrict__ Kc, ushort* __restrict__ Vt)
{
  const int t = blockIdx.x * 256 + threadIdx.x;
  const int bl = t >> 16;
  const int g  = (t >> 8) & 255;
  const int lq = t & 255;
  const int i = lq >> 3, j4 = (lq & 7) << 2;
  const float* xb = x + (((size_t)bl * 256 + g) << 12) + (2 * i) * 64 + 2 * j4;
  union { float4 v[2]; float f[8]; } xr0, xr1;
  xr0.v[0] = *(const float4*)(xb);
  xr0.v[1] = *(const float4*)(xb + 4);
  xr1.v[0] = *(const float4*)(xb + 64);
  xr1.v[1] = *(const float4*)(xb + 68);
  const int bhl = bl * 8 + (g >> 5);
  const int c2b = (g & 31) * 8;
  const int l0 = i * 32 + j4;
  #pragma unroll
  for (int h = 0; h < 8; ++h) {
    float4 w4 = *(const float4*)(Wq + g * 32 + h * 4);
    float bb = bq[g * 8 + h];
    union { ushort u[4]; uint2 q; } o;
    #pragma unroll
    for (int jj = 0; jj < 4; ++jj) {
      float v = xr0.f[2 * jj] * w4.x + xr0.f[2 * jj + 1] * w4.y
              + xr1.f[2 * jj] * w4.z + xr1.f[2 * jj + 1] * w4.w + bb;
      o.u[jj] = f2bf(v * 0.03125f);
    }
    *(uint2*)(Qc + (((size_t)bhl * 256 + c2b + h) << 10) + l0) = o.q;
  }
  #pragma unroll
  for (int h = 0; h < 8; ++h) {
    float4 w4 = *(const float4*)(Wk + g * 32 + h * 4);
    float bb = bk[g * 8 + h];
    union { ushort u[4]; uint2 q; } o;
    #pragma unroll
    for (int jj = 0; jj < 4; ++jj) {
      float v = xr0.f[2 * jj] * w4.x + xr0.f[2 * jj + 1] * w4.y
              + xr1.f[2 * jj] * w4.z + xr1.f[2 * jj + 1] * w4.w + bb;
      o.u[jj] = f2bf(v);
    }
    *(uint2*)(Kc + (((size_t)bhl * 256 + c2b + h) << 10) + l0) = o.q;
  }
  ushort vo[4][8];
  #pragma unroll
  for (int h = 0; h < 8; ++h) {
    float4 w4 = *(const float4*)(Wv + g * 32 + h * 4);
    float bb = bv[g * 8 + h];
    #pragma unroll
    for (int jj = 0; jj < 4; ++jj) {
      float v = xr0.f[2 * jj] * w4.x + xr0.f[2 * jj + 1] * w4.y
              + xr1.f[2 * jj] * w4.z + xr1.f[2 * jj + 1] * w4.w + bb;
      vo[jj][h] = f2bf(v);
    }
  }
  #pragma unroll
  for (int jj = 0; jj < 4; ++jj)
    *(uint4*)(Vt + ((size_t)bhl << 18) + (size_t)(l0 + jj) * 256 + c2b) =
        *(uint4*)&vo[jj][0];
}

// ------- C1: scores = qc @ kc^T, bf16 MFMA, K=1024 (half-batch) -------------
__global__ __launch_bounds__(256) void k_cha_scores_mfma(
    const ushort* __restrict__ Qc, const ushort* __restrict__ Kc,
    float* __restrict__ S)
{
  const int c0 = blockIdx.x * 128, d0 = blockIdx.y * 128, bhl = blockIdx.z;
  const int tid = threadIdx.x, lane = tid & 63, w = tid >> 6;
  __shared__ ushort As[128][32], Bs[128][32];
  const ushort* Ab = Qc + ((size_t)bhl * 256 + c0) * 1024;
  const ushort* Bb = Kc + ((size_t)bhl * 256 + d0) * 1024;
  const int wr = w >> 1, wc = w & 1;
  f32x4 acc[4][4];
  #pragma unroll
  for (int mi = 0; mi < 4; ++mi)
    #pragma unroll
    for (int ni = 0; ni < 4; ++ni) {
      f32x4 z = {0.f, 0.f, 0.f, 0.f};
      acc[mi][ni] = z;
    }
  for (int kc = 0; kc < 1024; kc += 32) {
    __syncthreads();
    #pragma unroll
    for (int q = 0; q < 2; ++q) {
      int idx = w * 128 + q * 64 + lane;
      int row = idx >> 2, seg = idx & 3;
      const ushort* srcA = Ab + (size_t)row * 1024 + kc + seg * 8;
      const ushort* srcB = Bb + (size_t)row * 1024 + kc + seg * 8;
      char* dstA = (char*)&As[0][0] + w * 2048 + q * 1024;
      char* dstB = (char*)&Bs[0][0] + w * 2048 + q * 1024;
      __builtin_amdgcn_global_load_lds(
          (const __attribute__((address_space(1))) unsigned*)srcA,
          (__attribute__((address_space(3))) unsigned*)dstA, 16, 0, 0);
      __builtin_amdgcn_global_load_lds(
          (const __attribute__((address_space(1))) unsigned*)srcB,
          (__attribute__((address_space(3))) unsigned*)dstB, 16, 0, 0);
    }
    __syncthreads();
    bf16x8 af[4], bfv[4];
    #pragma unroll
    for (int mi = 0; mi < 4; ++mi)
      af[mi] = *(const bf16x8*)&As[wr * 64 + mi * 16 + (lane & 15)][(lane >> 4) * 8];
    #pragma unroll
    for (int ni = 0; ni < 4; ++ni)
      bfv[ni] = *(const bf16x8*)&Bs[wc * 64 + ni * 16 + (lane & 15)][(lane >> 4) * 8];
    #pragma unroll
    for (int mi = 0; mi < 4; ++mi)
      #pragma unroll
      for (int ni = 0; ni < 4; ++ni)
        acc[mi][ni] = __builtin_amdgcn_mfma_f32_16x16x32_bf16(
            af[mi], bfv[ni], acc[mi][ni], 0, 0, 0);
  }
  float* Sb = S + ((size_t)bhl << 16);
  #pragma unroll
  for (int mi = 0; mi < 4; ++mi)
    #pragma unroll
    for (int r = 0; r < 4; ++r) {
      int c = c0 + wr * 64 + mi * 16 + (lane >> 4) * 4 + r;
      #pragma unroll
      for (int ni = 0; ni < 4; ++ni) {
        int d = d0 + wc * 64 + ni * 16 + (lane & 15);
        Sb[(size_t)c * 256 + d] = acc[mi][ni][r];
      }
    }
}

// ------- C2: row softmax over 256 -> bf16 P ---------------------------------
__global__ __launch_bounds__(256) void k_softmax_p(
    const float* __restrict__ S, ushort* __restrict__ P)
{
  const int row = blockIdx.x * 4 + (threadIdx.x >> 6);
  const int lane = threadIdx.x & 63;
  const float* r = S + (size_t)row * 256;
  float4 v = *(const float4*)(r + lane * 4);
  float m = fmaxf(fmaxf(v.x, v.y), fmaxf(v.z, v.w));
  #pragma unroll
  for (int off = 32; off; off >>= 1) m = fmaxf(m, __shfl_xor(m, off, 64));
  v.x = __expf(v.x - m); v.y = __expf(v.y - m);
  v.z = __expf(v.z - m); v.w = __expf(v.w - m);
  float s = v.x + v.y + v.z + v.w;
  #pragma unroll
  for (int off = 32; off; off >>= 1) s += __shfl_xor(s, off, 64);
  const float inv = 1.f / s;
  union { ushort u[4]; uint2 q; } o;
  o.u[0] = f2bf(v.x * inv); o.u[1] = f2bf(v.y * inv);
  o.u[2] = f2bf(v.z * inv); o.u[3] = f2bf(v.w * inv);
  *(uint2*)(P + (size_t)row * 256 + lane * 4) = o.q;
}

// -- C3: oc = P @ vcT (MFMA) + grouped ConvT + residual -> fused_pad NHWC ----
__global__ __launch_bounds__(256) void k_cha_pv(
    const ushort* __restrict__ P, const ushort* __restrict__ Vt,
    const float* __restrict__ x,
    const float* __restrict__ Wt, const float* __restrict__ bt,
    const float* __restrict__ gamma, ushort* __restrict__ fused, int bbase)
{
  const int n0 = blockIdx.x * 128, c0 = blockIdx.y * 128, bhl = blockIdx.z;
  const int b = bbase + (bhl >> 3), h = bhl & 7;
  const int tid = threadIdx.x, lane = tid & 63, w = tid >> 6;
  __shared__ ushort As[128][32], Bs[128][32];
  __shared__ ushort Ot[512][16];   // [local up-pixel][channel]
  __shared__ float wt_s[16][32];
  __shared__ float bt_s[16];
  const int gp_base = h * 32 + (c0 >> 3);
  {
    int e = tid;
    wt_s[e >> 5][e & 31] = Wt[(size_t)gp_base * 32 + e];
    e += 256;
    wt_s[e >> 5][e & 31] = Wt[(size_t)gp_base * 32 + e];
    if (tid < 16) bt_s[tid] = bt[gp_base + tid];
  }
  const ushort* Ab = P + (((size_t)bhl << 8) + c0) * 256;
  const ushort* Bb = Vt + ((size_t)bhl << 18) + (size_t)n0 * 256;
  const int wr = w >> 1, wc = w & 1;
  f32x4 acc[4][4];
  #pragma unroll
  for (int mi = 0; mi < 4; ++mi)
    #pragma unroll
    for (int ni = 0; ni < 4; ++ni) {
      f32x4 z = {0.f, 0.f, 0.f, 0.f};
      acc[mi][ni] = z;
    }
  for (int kc = 0; kc < 256; kc += 32) {
    __syncthreads();
    #pragma unroll
    for (int q = 0; q < 2; ++q) {
      int idx = w * 128 + q * 64 + lane;
      int row = idx >> 2, seg = idx & 3;
      const ushort* srcA = Ab + (size_t)row * 256 + kc + seg * 8;
      const ushort* srcB = Bb + (size_t)row * 256 + kc + seg * 8;
      char* dstA = (char*)&As[0][0] + w * 2048 + q * 1024;
      char* dstB = (char*)&Bs[0][0] + w * 2048 + q * 1024;
      __builtin_amdgcn_global_load_lds(
          (const __attribute__((address_space(1))) unsigned*)srcA,
          (__attribute__((address_space(3))) unsigned*)dstA, 16, 0, 0);
      __builtin_amdgcn_global_load_lds(
          (const __attribute__((address_space(1))) unsigned*)srcB,
          (__attribute__((address_space(3))) unsigned*)dstB, 16, 0, 0);
    }
    __syncthreads();
    bf16x8 af[4], bfv[4];
    #pragma unroll
    for (int mi = 0; mi < 4; ++mi)
      af[mi] = *(const bf16x8*)&As[wr * 64 + mi * 16 + (lane & 15)][(lane >> 4) * 8];
    #pragma unroll
    for (int ni = 0; ni < 4; ++ni)
      bfv[ni] = *(const bf16x8*)&Bs[wc * 64 + ni * 16 + (lane & 15)][(lane >> 4) * 8];
    #pragma unroll
    for (int mi = 0; mi < 4; ++mi)
      #pragma unroll
      for (int ni = 0; ni < 4; ++ni)
        acc[mi][ni] = __builtin_amdgcn_mfma_f32_16x16x32_bf16(
            af[mi], bfv[ni], acc[mi][ni], 0, 0, 0);
  }
  // stage 1: ConvTranspose + residual into Ot (LDS)
  const float gm = gamma[0];
  const int col = lane & 15, q = lane >> 4;
  #pragma unroll
  for (int mi = 0; mi < 4; ++mi) {
    const int gloc = wr * 8 + mi * 2 + (q >> 1);
    const int gp = gp_base + gloc;
    const float btv = bt_s[gloc];
    #pragma unroll
    for (int ni = 0; ni < 4; ++ni) {
      float pa[4] = {0.f, 0.f, 0.f, 0.f};
      #pragma unroll
      for (int r = 0; r < 4; ++r) {
        const int i2 = (q & 1) * 4 + r;
        const float a = acc[mi][ni][r];
        pa[0] += a * wt_s[gloc][i2 * 4 + 0];
        pa[1] += a * wt_s[gloc][i2 * 4 + 1];
        pa[2] += a * wt_s[gloc][i2 * 4 + 2];
        pa[3] += a * wt_s[gloc][i2 * 4 + 3];
      }
      float v0 = pa[0] + __shfl_xor(pa[0], 16, 64);
      float v1 = pa[1] + __shfl_xor(pa[1], 16, 64);
      float v2 = pa[2] + __shfl_xor(pa[2], 16, 64);
      float v3 = pa[3] + __shfl_xor(pa[3], 16, 64);
      const int lloc = wc * 64 + ni * 16 + col;
      const int l = n0 + lloc;
      const int p = l >> 5, j = l & 31;
      const int y = 2 * p + (q & 1);
      const float va = (q & 1) ? v2 : v0;
      const float vb = (q & 1) ? v3 : v1;
      const float* xc = x + (((size_t)b * 256 + gp) << 12) + (y << 6) + 2 * j;
      const int lp = (lloc << 2) + (q & 1) * 2;
      Ot[lp][gloc]     = f2bf(xc[0] + gm * (va + btv));
      Ot[lp + 1][gloc] = f2bf(xc[1] + gm * (vb + btv));
    }
  }
  __syncthreads();
  // stage 2: write NHWC padded, 32B per up-pixel
  #pragma unroll
  for (int pp2 = 0; pp2 < 2; ++pp2) {
    const int pixl = tid * 2 + pp2;
    const int lloc = pixl >> 2;
    const int l = n0 + lloc;
    const int p = l >> 5, j = l & 31;
    const int yy = 2 * p + ((pixl >> 1) & 1) + 1;
    const int xx = 2 * j + (pixl & 1) + 1;
    const uint4* src = (const uint4*)&Ot[pixl][0];
    uint4* dst = (uint4*)(fused + ((size_t)b * 4356 + yy * 66 + xx) * 512 + 256 + gp_base);
    dst[0] = src[0];
    dst[1] = src[1];
  }
}

extern "C" void kernel_launch(void* const* d_in, const int* in_sizes, int n_in,
                              void* d_out, int out_size, void* d_ws, size_t ws_size,
                              hipStream_t stream)
{
  (void)in_sizes; (void)n_in; (void)out_size; (void)ws_size;
  const float* qkv_pos   = (const float*)d_in[0];
  const float* qkv_cha   = (const float*)d_in[1];
  const float* Wq_pos    = (const float*)d_in[2];
  const float* bq_pos    = (const float*)d_in[3];
  const float* Wk_pos    = (const float*)d_in[4];
  const float* bk_pos    = (const float*)d_in[5];
  const float* Wv_pos    = (const float*)d_in[6];
  const float* bv_pos    = (const float*)d_in[7];
  const float* Wo_pos    = (const float*)d_in[8];
  const float* bo_pos    = (const float*)d_in[9];
  const float* gamma_pos = (const float*)d_in[10];
  const float* Wq_cha    = (const float*)d_in[11];
  const float* bq_cha    = (const float*)d_in[12];
  const float* Wk_cha    = (const float*)d_in[13];
  const float* bk_cha    = (const float*)d_in[14];
  const float* Wv_cha    = (const float*)d_in[15];
  const float* bv_cha    = (const float*)d_in[16];
  const float* Wt_cha    = (const float*)d_in[17];
  const float* bt_cha    = (const float*)d_in[18];
  const float* gamma_cha = (const float*)d_in[19];
  const float* Wf        = (const float*)d_in[20];
  const float* bf        = (const float*)d_in[21];
  float* out = (float*)d_out;

  float* ws = (float*)d_ws;
  ushort* Wpf9    = (ushort*)ws;
  ushort* Wpo9    = (ushort*)(ws + 589824);
  // POS scratch
  float*  Qp      = ws + 884736;
  float*  Kp      = Qp + 524288;
  float*  Vp      = Kp + 524288;
  ushort* op_pad  = (ushort*)(ws + 4030464);   // 2367488 ushorts
  float*  op_conv = ws + 5214208;              // NHWC fp32 [8][1024][256]
  // CHA scratch (aliases POS region after it is consumed)
  ushort* qcb     = (ushort*)(ws + 884736);
  ushort* kcb     = (ushort*)(ws + 5079040);
  ushort* vcT     = (ushort*)(ws + 9273344);
  float*  attn_c  = ws + 13467648;
  ushort* Pb      = (ushort*)(ws + 15564800);
  ushort* fusedb  = (ushort*)(ws + 16613376);  // NHWC padded [8][66*66][512]

  // zero the padded NHWC buffers (borders must be 0)
  hipMemsetAsync(op_pad, 0, (size_t)2367488 * 2, stream);
  hipMemsetAsync(fusedb, 0, (size_t)17842176 * 2, stream);
  // weight pre-pack to [t][oc][c] bf16
  k_prepack9<512><<<dim3(4608), 256, 0, stream>>>(Wf, Wpf9);
  k_prepack9<256><<<dim3(2304), 256, 0, stream>>>(Wo_pos, Wpo9);
  // POS branch
  k_pos_qkv<<<dim3(6, 16, 8), 256, 0, stream>>>(qkv_pos, Wq_pos, bq_pos,
      Wk_pos, bk_pos, Wv_pos, bv_pos, Qp, Kp, Vp);
  k_pos_attn<<<dim3(64, 8, 8), 256, 0, stream>>>(Qp, Kp, Vp, op_pad);
  k_conv9_mfma<256, 32, 34, 1><<<dim3(8, 2, 8), 256, 0, stream>>>(
      op_pad, Wpo9, bo_pos, op_conv);
  k_upsample_nhwc<<<dim3(8192), 256, 0, stream>>>(qkv_pos, op_conv, gamma_pos, fusedb);
  // CHA branch, two half-batches
  for (int half = 0; half < 2; ++half) {
    const float* xh = qkv_cha + (size_t)half * 4 * 256 * 4096;
    k_cha_proj<<<dim3(1024), 256, 0, stream>>>(xh, Wq_cha, bq_cha,
        Wk_cha, bk_cha, Wv_cha, bv_cha, qcb, kcb, vcT);
    k_cha_scores_mfma<<<dim3(2, 2, 32), 256, 0, stream>>>(qcb, kcb, attn_c);
    k_softmax_p<<<dim3(2048), 256, 0, stream>>>(attn_c, Pb);
    k_cha_pv<<<dim3(8, 2, 32), 256, 0, stream>>>(Pb, vcT, qkv_cha,
        Wt_cha, bt_cha, gamma_cha, fusedb, half * 4);
  }
  // fusion conv (bf16 MFMA over padded NHWC)
  k_conv9_mfma<512, 64, 66, 0><<<dim3(32, 2, 8), 256, 0, stream>>>(
      fusedb, Wpf9, bf, out);
}

// Round 5
// 730.627 us; speedup vs baseline: 3.8780x; 1.3387x over previous
//
#include <hip/hip_runtime.h>
#include <math.h>

// Shapes: B=8, C=256, H=W=64, HQ=WQ=32, L=1024, NH=8, hd=8, dv=32
//
// Workspace (float units):
//   Wpf9 bf16[9][256][512] @ 0        (589824 f)
//   Wpo9 bf16[9][256][256] @ 589824   (294912 f)
//   region2 @ 884736 (POS scratch, later aliased by CHA scratch):
//     POS: Qb bf16[64][1024][32] @884736  (1048576 f, hd pad zeroed)
//          Kb bf16[64][1024][32] @1933312 (1048576 f)
//          Vtb bf16[64][32][1024] @2981888 (1048576 f)
//          op_pad bf16[8][34*34][256] @4030464 (1183744 f)
//          op_conv f32 NHWC [8][1024][256] @5214208 (2097152 f)
//     CHA: qcb bf16 @884736 | kcb @5079040 | vcT @9273344 (4194304 f each)
//          attn_c f32 @13467648 (2097152) | P bf16 @15564800 (1048576 f)
//   fused_pad bf16[8][66*66][512] @ 16613376 (8921088 f)

typedef __attribute__((ext_vector_type(8))) short bf16x8;
typedef __attribute__((ext_vector_type(4))) float f32x4;

__device__ __forceinline__ ushort f2bf(float f) {
  union { float f; unsigned u; } v; v.f = f;
  unsigned r = (v.u + 0x7FFFu + ((v.u >> 16) & 1u)) >> 16;
  return (ushort)r;
}

// -------- weight pre-pack: W[oc][cin][3][3] fp32 -> [t][oc][cin] bf16 -------
template <int CIN>
__global__ __launch_bounds__(256) void k_prepack9(
    const float* __restrict__ W, ushort* __restrict__ out)
{
  const int i = blockIdx.x * 256 + threadIdx.x;   // over 9*256*CIN
  const int t = i / (256 * CIN);
  const int r = i - t * (256 * CIN);
  const int oc = r / CIN;
  const int c = r - oc * CIN;
  out[i] = f2bf(W[((size_t)oc * CIN + c) * 9 + t]);
}

// ---- P1: POS q/k/v projection (stride-2 conv as GEMM) -> bf16 MFMA layouts -
__global__ __launch_bounds__(256) void k_pos_qkv(
    const float* __restrict__ x,
    const float* __restrict__ Wq, const float* __restrict__ bq,
    const float* __restrict__ Wk, const float* __restrict__ bk,
    const float* __restrict__ Wv, const float* __restrict__ bv,
    ushort* __restrict__ Qb, ushort* __restrict__ Kb, ushort* __restrict__ Vtb)
{
  const int ot = blockIdx.x, lt = blockIdx.y, b = blockIdx.z;
  const int tid = threadIdx.x;
  __shared__ float At[64][68];
  __shared__ float Bt[64][68];
  const int l0 = lt * 64, o0 = ot * 64;
  int base; const float* Wsel; const float* bsel;
  if (ot == 0)      { base = 0;   Wsel = Wq; bsel = bq; }
  else if (ot == 1) { base = 64;  Wsel = Wk; bsel = bk; }
  else              { base = 128; Wsel = Wv; bsel = bv; }
  const int lj = (tid & 15) * 4, oi = (tid >> 4) * 4;
  float acc[4][4] = {};
  const float* xb = x + (size_t)b * 256 * 4096;
  for (int kc = 0; kc < 1024; kc += 64) {
    #pragma unroll
    for (int e0 = 0; e0 < 16; ++e0) {
      int e = e0 * 256 + tid;
      int kk = e >> 6, ll = e & 63;
      int k = kc + kk;
      int c = k >> 2, uv = k & 3;
      int l = l0 + ll;
      int y = 2 * (l >> 5) + (uv >> 1), xx = 2 * (l & 31) + (uv & 1);
      At[kk][ll] = xb[((size_t)c << 12) + (y << 6) + xx];
    }
    #pragma unroll
    for (int e0 = 0; e0 < 16; ++e0) {
      int e = e0 * 256 + tid;
      int oo = e >> 6, kk = e & 63;
      Bt[kk][oo] = Wsel[(size_t)(o0 - base + oo) * 1024 + kc + kk];
    }
    __syncthreads();
    #pragma unroll 16
    for (int kk = 0; kk < 64; ++kk) {
      float a[4], w[4];
      *(float4*)a = *(const float4*)&At[kk][lj];
      *(float4*)w = *(const float4*)&Bt[kk][oi];
      #pragma unroll
      for (int ii = 0; ii < 4; ++ii)
        #pragma unroll
        for (int jj = 0; jj < 4; ++jj)
          acc[ii][jj] += w[ii] * a[jj];
    }
    __syncthreads();
  }
  #pragma unroll
  for (int ii = 0; ii < 4; ++ii) {
    const int o = o0 + oi + ii;
    const float bias = bsel[o - base];
    #pragma unroll
    for (int jj = 0; jj < 4; ++jj) {
      const int l = l0 + lj + jj;
      const float val = acc[ii][jj] + bias;
      if (o < 64) {
        int hh = o >> 3, e = o & 7;   // scale folded into Q
        Qb[(((((size_t)b * 8 + hh) << 10) + l) << 5) + e] =
            f2bf(val * 0.35355339059327373f);
      } else if (o < 128) {
        int o2 = o - 64, hh = o2 >> 3, e = o2 & 7;
        Kb[(((((size_t)b * 8 + hh) << 10) + l) << 5) + e] = f2bf(val);
      } else {
        int o2 = o - 128, hh = o2 >> 5, d = o2 & 31;
        Vtb[(((size_t)b * 8 + hh) * 32 + d << 10) + l] = f2bf(val);
      }
    }
  }
}

// ---- P2: flash POS attention, bf16 MFMA, no barriers -----------------------
// Qb/Kb: bf16 [bh][1024][32] (k>=8 of Qb zero); Vtb: bf16 [bh][32][1024]
// out: op_pad NHWC padded bf16 [b][34*34][256]
__global__ __launch_bounds__(256) void k_pos_flash(
    const ushort* __restrict__ Qb, const ushort* __restrict__ Kb,
    const ushort* __restrict__ Vtb, ushort* __restrict__ op_pad)
{
  const int qt = blockIdx.x, h = blockIdx.y, b = blockIdx.z;
  const int bh = b * 8 + h;
  const int tid = threadIdx.x, lane = tid & 63, wq = tid >> 6;
  const int c = lane & 15, g = lane >> 4;
  __shared__ __align__(16) ushort Ps[4][32][72];   // wave-private P tiles
  const int qbase = qt * 128 + wq * 32;
  // Q B-fragments (held for the whole kernel)
  bf16x8 qf[2];
  #pragma unroll
  for (int nt = 0; nt < 2; ++nt)
    qf[nt] = *(const bf16x8*)(Qb + (((size_t)bh << 10) + qbase + nt * 16 + c) * 32 + g * 8);
  f32x4 o[2][2];
  #pragma unroll
  for (int mt = 0; mt < 2; ++mt)
    #pragma unroll
    for (int nt = 0; nt < 2; ++nt) {
      f32x4 z = {0.f, 0.f, 0.f, 0.f};
      o[mt][nt] = z;
    }
  float m[2] = {-1e30f, -1e30f}, l[2] = {0.f, 0.f};
  const ushort* Kbh = Kb + ((size_t)bh << 15);
  const ushort* Vbh = Vtb + ((size_t)bh << 15);

  for (int kt = 0; kt < 16; ++kt) {
    const int kb0 = kt * 64;
    // S^T = K . Q^T  (m=key, n=q, k=hd padded to 32)
    bf16x8 kf[4];
    #pragma unroll
    for (int mt = 0; mt < 4; ++mt)
      kf[mt] = *(const bf16x8*)(Kbh + (size_t)(kb0 + mt * 16 + c) * 32 + g * 8);
    f32x4 s[4][2];
    #pragma unroll
    for (int mt = 0; mt < 4; ++mt)
      #pragma unroll
      for (int nt = 0; nt < 2; ++nt) {
        f32x4 z = {0.f, 0.f, 0.f, 0.f};
        s[mt][nt] = __builtin_amdgcn_mfma_f32_16x16x32_bf16(kf[mt], qf[nt], z, 0, 0, 0);
      }
    // online softmax per q (q = lane&15 within n-tile -> per-lane scalars)
    #pragma unroll
    for (int nt = 0; nt < 2; ++nt) {
      float tmax = -1e30f;
      #pragma unroll
      for (int mt = 0; mt < 4; ++mt)
        #pragma unroll
        for (int r = 0; r < 4; ++r)
          tmax = fmaxf(tmax, s[mt][nt][r]);
      tmax = fmaxf(tmax, __shfl_xor(tmax, 16, 64));
      tmax = fmaxf(tmax, __shfl_xor(tmax, 32, 64));
      const float mn = fmaxf(m[nt], tmax);
      const float alpha = __expf(m[nt] - mn);
      m[nt] = mn;
      float rs = 0.f;
      #pragma unroll
      for (int mt = 0; mt < 4; ++mt) {
        union { ushort u[4]; uint2 d; } pk;
        #pragma unroll
        for (int r = 0; r < 4; ++r) {
          float p = __expf(s[mt][nt][r] - mn);
          rs += p;
          pk.u[r] = f2bf(p);
        }
        *(uint2*)&Ps[wq][nt * 16 + c][mt * 16 + g * 4] = pk.d;
      }
      rs += __shfl_xor(rs, 16, 64);
      rs += __shfl_xor(rs, 32, 64);
      l[nt] = l[nt] * alpha + rs;
      #pragma unroll
      for (int mt = 0; mt < 2; ++mt)
        #pragma unroll
        for (int r = 0; r < 4; ++r)
          o[mt][nt][r] *= alpha;
    }
    // O^T += V^T . P^T  (m=d, n=q, k=key)
    #pragma unroll
    for (int kc = 0; kc < 2; ++kc) {
      bf16x8 vf[2], pf[2];
      #pragma unroll
      for (int mt = 0; mt < 2; ++mt)
        vf[mt] = *(const bf16x8*)(Vbh + (size_t)(mt * 16 + c) * 1024 + kb0 + kc * 32 + g * 8);
      #pragma unroll
      for (int nt = 0; nt < 2; ++nt)
        pf[nt] = *(const bf16x8*)&Ps[wq][nt * 16 + c][kc * 32 + g * 8];
      #pragma unroll
      for (int mt = 0; mt < 2; ++mt)
        #pragma unroll
        for (int nt = 0; nt < 2; ++nt)
          o[mt][nt] = __builtin_amdgcn_mfma_f32_16x16x32_bf16(vf[mt], pf[nt], o[mt][nt], 0, 0, 0);
    }
  }
  // epilogue: O/l -> NHWC padded bf16
  #pragma unroll
  for (int nt = 0; nt < 2; ++nt) {
    const float linv = 1.f / l[nt];
    const int q = qbase + nt * 16 + c;
    const int y = q >> 5, x = q & 31;
    ushort* dst = op_pad + ((size_t)b * 1156 + (y + 1) * 34 + (x + 1)) * 256 + h * 32;
    #pragma unroll
    for (int mt = 0; mt < 2; ++mt) {
      union { ushort u[4]; uint2 d; } pk;
      #pragma unroll
      for (int r = 0; r < 4; ++r)
        pk.u[r] = f2bf(o[mt][nt][r] * linv);
      *(uint2*)(dst + mt * 16 + g * 4) = pk.d;
    }
  }
}

// ------ 3x3 conv as 9 shifted GEMMs over padded NHWC, bf16 MFMA -------------
template <int CIN, int S, int PW, int OUT_NHWC>
__global__ __launch_bounds__(256) void k_conv9_mfma(
    const ushort* __restrict__ in, const ushort* __restrict__ W9,
    const float* __restrict__ bias, float* __restrict__ out)
{
  const int n0 = blockIdx.x * 128, oc0 = blockIdx.y * 128, b = blockIdx.z;
  const int tid = threadIdx.x, lane = tid & 63, w = tid >> 6;
  __shared__ ushort As[128][32], Bs[128][32];
  const int wr = w >> 1, wc = w & 1;
  f32x4 acc[4][4];
  #pragma unroll
  for (int mi = 0; mi < 4; ++mi)
    #pragma unroll
    for (int ni = 0; ni < 4; ++ni) {
      f32x4 z = {0.f, 0.f, 0.f, 0.f};
      acc[mi][ni] = z;
    }
  int rowq[2], segq[2], basep[2];
  #pragma unroll
  for (int q = 0; q < 2; ++q) {
    int idx = w * 128 + q * 64 + lane;
    rowq[q] = idx >> 2;
    segq[q] = (idx & 3) * 8;
    int n = n0 + rowq[q];
    int y = n / S, x = n % S;
    basep[q] = y * PW + x;
  }
  const ushort* inb = in + (size_t)b * (PW * PW) * CIN;

  for (int t = 0; t < 9; ++t) {
    const int offp = (t / 3) * PW + (t % 3);
    const ushort* wt = W9 + (size_t)t * 256 * CIN;
    for (int kc = 0; kc < CIN; kc += 32) {
      __syncthreads();
      #pragma unroll
      for (int q = 0; q < 2; ++q) {
        const ushort* srcA = wt + (size_t)(oc0 + rowq[q]) * CIN + kc + segq[q];
        const ushort* srcB = inb + (size_t)(basep[q] + offp) * CIN + kc + segq[q];
        char* dstA = (char*)&As[0][0] + w * 2048 + q * 1024;
        char* dstB = (char*)&Bs[0][0] + w * 2048 + q * 1024;
        __builtin_amdgcn_global_load_lds(
            (const __attribute__((address_space(1))) unsigned*)srcA,
            (__attribute__((address_space(3))) unsigned*)dstA, 16, 0, 0);
        __builtin_amdgcn_global_load_lds(
            (const __attribute__((address_space(1))) unsigned*)srcB,
            (__attribute__((address_space(3))) unsigned*)dstB, 16, 0, 0);
      }
      __syncthreads();
      bf16x8 af[4], bfv[4];
      #pragma unroll
      for (int mi = 0; mi < 4; ++mi)
        af[mi] = *(const bf16x8*)&As[wr * 64 + mi * 16 + (lane & 15)][(lane >> 4) * 8];
      #pragma unroll
      for (int ni = 0; ni < 4; ++ni)
        bfv[ni] = *(const bf16x8*)&Bs[wc * 64 + ni * 16 + (lane & 15)][(lane >> 4) * 8];
      #pragma unroll
      for (int mi = 0; mi < 4; ++mi)
        #pragma unroll
        for (int ni = 0; ni < 4; ++ni)
          acc[mi][ni] = __builtin_amdgcn_mfma_f32_16x16x32_bf16(
              af[mi], bfv[ni], acc[mi][ni], 0, 0, 0);
    }
  }
  if (OUT_NHWC) {
    float* outb = out + (size_t)b * (S * S) * 256;
    #pragma unroll
    for (int mi = 0; mi < 4; ++mi) {
      const int oc = oc0 + wr * 64 + mi * 16 + (lane >> 4) * 4;
      float4 bb = *(const float4*)(bias + oc);
      #pragma unroll
      for (int ni = 0; ni < 4; ++ni) {
        const int n = n0 + wc * 64 + ni * 16 + (lane & 15);
        float4 v;
        v.x = acc[mi][ni][0] + bb.x;
        v.y = acc[mi][ni][1] + bb.y;
        v.z = acc[mi][ni][2] + bb.z;
        v.w = acc[mi][ni][3] + bb.w;
        *(float4*)(outb + (size_t)n * 256 + oc) = v;
      }
    }
  } else {
    float* outb = out + (size_t)b * 256 * (S * S);
    #pragma unroll
    for (int mi = 0; mi < 4; ++mi) {
      #pragma unroll
      for (int r = 0; r < 4; ++r) {
        int oc = oc0 + wr * 64 + mi * 16 + (lane >> 4) * 4 + r;
        float bb = bias[oc];
        #pragma unroll
        for (int ni = 0; ni < 4; ++ni) {
          int n = n0 + wc * 64 + ni * 16 + (lane & 15);
          outb[(size_t)oc * (S * S) + n] = acc[mi][ni][r] + bb;
        }
      }
    }
  }
}

// ---- P4: bilinear x2 upsample + residual -> fused_pad[.., ch 0:256] --------
__global__ __launch_bounds__(256) void k_upsample_nhwc(
    const float* __restrict__ xpos, const float* __restrict__ opc,
    const float* __restrict__ gamma, ushort* __restrict__ fused)
{
  const int t = blockIdx.x * 256 + threadIdx.x;  // 8*4096*64
  const int c = (t & 63) * 4;
  const int pix = (t >> 6) & 4095;
  const int b = t >> 18;
  const int y = pix >> 6, xx = pix & 63;
  const int my = y >> 1;
  const int y0 = (y & 1) ? my : my - 1;
  const float fy = (y & 1) ? 0.25f : 0.75f;
  const int mx = xx >> 1;
  const int x0 = (xx & 1) ? mx : mx - 1;
  const float fx = (xx & 1) ? 0.25f : 0.75f;
  const int y0c = max(y0, 0), y1c = min(y0 + 1, 31);
  const int x0c = max(x0, 0), x1c = min(x0 + 1, 31);
  const float* base = opc + (size_t)b * 1024 * 256 + c;
  float4 v00 = *(const float4*)(base + (size_t)(y0c * 32 + x0c) * 256);
  float4 v01 = *(const float4*)(base + (size_t)(y0c * 32 + x1c) * 256);
  float4 v10 = *(const float4*)(base + (size_t)(y1c * 32 + x0c) * 256);
  float4 v11 = *(const float4*)(base + (size_t)(y1c * 32 + x1c) * 256);
  const float w00 = (1.f - fy) * (1.f - fx), w01 = (1.f - fy) * fx;
  const float w10 = fy * (1.f - fx), w11 = fy * fx;
  const float g = gamma[0];
  const float* xr = xpos + ((size_t)b * 256 + c) * 4096 + pix;
  union { ushort u[4]; uint2 q; } o;
  o.u[0] = f2bf(xr[0]          + g * (w00 * v00.x + w01 * v01.x + w10 * v10.x + w11 * v11.x));
  o.u[1] = f2bf(xr[4096]       + g * (w00 * v00.y + w01 * v01.y + w10 * v10.y + w11 * v11.y));
  o.u[2] = f2bf(xr[2 * 4096]   + g * (w00 * v00.z + w01 * v01.z + w10 * v10.z + w11 * v11.z));
  o.u[3] = f2bf(xr[3 * 4096]   + g * (w00 * v00.w + w01 * v01.w + w10 * v10.w + w11 * v11.w));
  *(uint2*)(fused + ((size_t)b * 4356 + (y + 1) * 66 + (xx + 1)) * 512 + c) = o.q;
}

// ------- C0: CHA q/k/v grouped 2x2 projections -> bf16 (half-batch) ---------
__global__ __launch_bounds__(256) void k_cha_proj(
    const float* __restrict__ x,
    const float* __restrict__ Wq, const float* __restrict__ bq,
    const float* __restrict__ Wk, const float* __restrict__ bk,
    const float* __restrict__ Wv, const float* __restrict__ bv,
    ushort* __restrict__ Qc, ushort* __restrict__ Kc, ushort* __restrict__ Vt)
{
  const int t = blockIdx.x * 256 + threadIdx.x;
  const int bl = t >> 16;
  const int g  = (t >> 8) & 255;
  const int lq = t & 255;
  const int i = lq >> 3, j4 = (lq & 7) << 2;
  const float* xb = x + (((size_t)bl * 256 + g) << 12) + (2 * i) * 64 + 2 * j4;
  union { float4 v[2]; float f[8]; } xr0, xr1;
  xr0.v[0] = *(const float4*)(xb);
  xr0.v[1] = *(const float4*)(xb + 4);
  xr1.v[0] = *(const float4*)(xb + 64);
  xr1.v[1] = *(const float4*)(xb + 68);
  const int bhl = bl * 8 + (g >> 5);
  const int c2b = (g & 31) * 8;
  const int l0 = i * 32 + j4;
  #pragma unroll
  for (int h = 0; h < 8; ++h) {
    float4 w4 = *(const float4*)(Wq + g * 32 + h * 4);
    float bb = bq[g * 8 + h];
    union { ushort u[4]; uint2 q; } o;
    #pragma unroll
    for (int jj = 0; jj < 4; ++jj) {
      float v = xr0.f[2 * jj] * w4.x + xr0.f[2 * jj + 1] * w4.y
              + xr1.f[2 * jj] * w4.z + xr1.f[2 * jj + 1] * w4.w + bb;
      o.u[jj] = f2bf(v * 0.03125f);
    }
    *(uint2*)(Qc + (((size_t)bhl * 256 + c2b + h) << 10) + l0) = o.q;
  }
  #pragma unroll
  for (int h = 0; h < 8; ++h) {
    float4 w4 = *(const float4*)(Wk + g * 32 + h * 4);
    float bb = bk[g * 8 + h];
    union { ushort u[4]; uint2 q; } o;
    #pragma unroll
    for (int jj = 0; jj < 4; ++jj) {
      float v = xr0.f[2 * jj] * w4.x + xr0.f[2 * jj + 1] * w4.y
              + xr1.f[2 * jj] * w4.z + xr1.f[2 * jj + 1] * w4.w + bb;
      o.u[jj] = f2bf(v);
    }
    *(uint2*)(Kc + (((size_t)bhl * 256 + c2b + h) << 10) + l0) = o.q;
  }
  ushort vo[4][8];
  #pragma unroll
  for (int h = 0; h < 8; ++h) {
    float4 w4 = *(const float4*)(Wv + g * 32 + h * 4);
    float bb = bv[g * 8 + h];
    #pragma unroll
    for (int jj = 0; jj < 4; ++jj) {
      float v = xr0.f[2 * jj] * w4.x + xr0.f[2 * jj + 1] * w4.y
              + xr1.f[2 * jj] * w4.z + xr1.f[2 * jj + 1] * w4.w + bb;
      vo[jj][h] = f2bf(v);
    }
  }
  #pragma unroll
  for (int jj = 0; jj < 4; ++jj)
    *(uint4*)(Vt + ((size_t)bhl << 18) + (size_t)(l0 + jj) * 256 + c2b) =
        *(uint4*)&vo[jj][0];
}

// ------- C1: scores = qc @ kc^T, bf16 MFMA, K=1024 (half-batch) -------------
__global__ __launch_bounds__(256) void k_cha_scores_mfma(
    const ushort* __restrict__ Qc, const ushort* __restrict__ Kc,
    float* __restrict__ S)
{
  const int c0 = blockIdx.x * 128, d0 = blockIdx.y * 128, bhl = blockIdx.z;
  const int tid = threadIdx.x, lane = tid & 63, w = tid >> 6;
  __shared__ ushort As[128][32], Bs[128][32];
  const ushort* Ab = Qc + ((size_t)bhl * 256 + c0) * 1024;
  const ushort* Bb = Kc + ((size_t)bhl * 256 + d0) * 1024;
  const int wr = w >> 1, wc = w & 1;
  f32x4 acc[4][4];
  #pragma unroll
  for (int mi = 0; mi < 4; ++mi)
    #pragma unroll
    for (int ni = 0; ni < 4; ++ni) {
      f32x4 z = {0.f, 0.f, 0.f, 0.f};
      acc[mi][ni] = z;
    }
  for (int kc = 0; kc < 1024; kc += 32) {
    __syncthreads();
    #pragma unroll
    for (int q = 0; q < 2; ++q) {
      int idx = w * 128 + q * 64 + lane;
      int row = idx >> 2, seg = idx & 3;
      const ushort* srcA = Ab + (size_t)row * 1024 + kc + seg * 8;
      const ushort* srcB = Bb + (size_t)row * 1024 + kc + seg * 8;
      char* dstA = (char*)&As[0][0] + w * 2048 + q * 1024;
      char* dstB = (char*)&Bs[0][0] + w * 2048 + q * 1024;
      __builtin_amdgcn_global_load_lds(
          (const __attribute__((address_space(1))) unsigned*)srcA,
          (__attribute__((address_space(3))) unsigned*)dstA, 16, 0, 0);
      __builtin_amdgcn_global_load_lds(
          (const __attribute__((address_space(1))) unsigned*)srcB,
          (__attribute__((address_space(3))) unsigned*)dstB, 16, 0, 0);
    }
    __syncthreads();
    bf16x8 af[4], bfv[4];
    #pragma unroll
    for (int mi = 0; mi < 4; ++mi)
      af[mi] = *(const bf16x8*)&As[wr * 64 + mi * 16 + (lane & 15)][(lane >> 4) * 8];
    #pragma unroll
    for (int ni = 0; ni < 4; ++ni)
      bfv[ni] = *(const bf16x8*)&Bs[wc * 64 + ni * 16 + (lane & 15)][(lane >> 4) * 8];
    #pragma unroll
    for (int mi = 0; mi < 4; ++mi)
      #pragma unroll
      for (int ni = 0; ni < 4; ++ni)
        acc[mi][ni] = __builtin_amdgcn_mfma_f32_16x16x32_bf16(
            af[mi], bfv[ni], acc[mi][ni], 0, 0, 0);
  }
  float* Sb = S + ((size_t)bhl << 16);
  #pragma unroll
  for (int mi = 0; mi < 4; ++mi)
    #pragma unroll
    for (int r = 0; r < 4; ++r) {
      int c = c0 + wr * 64 + mi * 16 + (lane >> 4) * 4 + r;
      #pragma unroll
      for (int ni = 0; ni < 4; ++ni) {
        int d = d0 + wc * 64 + ni * 16 + (lane & 15);
        Sb[(size_t)c * 256 + d] = acc[mi][ni][r];
      }
    }
}

// ------- C2: row softmax over 256 -> bf16 P ---------------------------------
__global__ __launch_bounds__(256) void k_softmax_p(
    const float* __restrict__ S, ushort* __restrict__ P)
{
  const int row = blockIdx.x * 4 + (threadIdx.x >> 6);
  const int lane = threadIdx.x & 63;
  const float* r = S + (size_t)row * 256;
  float4 v = *(const float4*)(r + lane * 4);
  float m = fmaxf(fmaxf(v.x, v.y), fmaxf(v.z, v.w));
  #pragma unroll
  for (int off = 32; off; off >>= 1) m = fmaxf(m, __shfl_xor(m, off, 64));
  v.x = __expf(v.x - m); v.y = __expf(v.y - m);
  v.z = __expf(v.z - m); v.w = __expf(v.w - m);
  float s = v.x + v.y + v.z + v.w;
  #pragma unroll
  for (int off = 32; off; off >>= 1) s += __shfl_xor(s, off, 64);
  const float inv = 1.f / s;
  union { ushort u[4]; uint2 q; } o;
  o.u[0] = f2bf(v.x * inv); o.u[1] = f2bf(v.y * inv);
  o.u[2] = f2bf(v.z * inv); o.u[3] = f2bf(v.w * inv);
  *(uint2*)(P + (size_t)row * 256 + lane * 4) = o.q;
}

// -- C3: oc = P @ vcT (MFMA) + grouped ConvT + residual -> fused_pad NHWC ----
__global__ __launch_bounds__(256) void k_cha_pv(
    const ushort* __restrict__ P, const ushort* __restrict__ Vt,
    const float* __restrict__ x,
    const float* __restrict__ Wt, const float* __restrict__ bt,
    const float* __restrict__ gamma, ushort* __restrict__ fused, int bbase)
{
  const int n0 = blockIdx.x * 128, c0 = blockIdx.y * 128, bhl = blockIdx.z;
  const int b = bbase + (bhl >> 3), h = bhl & 7;
  const int tid = threadIdx.x, lane = tid & 63, w = tid >> 6;
  __shared__ ushort As[128][32], Bs[128][32];
  __shared__ ushort Ot[512][16];
  __shared__ float wt_s[16][32];
  __shared__ float bt_s[16];
  const int gp_base = h * 32 + (c0 >> 3);
  {
    int e = tid;
    wt_s[e >> 5][e & 31] = Wt[(size_t)gp_base * 32 + e];
    e += 256;
    wt_s[e >> 5][e & 31] = Wt[(size_t)gp_base * 32 + e];
    if (tid < 16) bt_s[tid] = bt[gp_base + tid];
  }
  const ushort* Ab = P + (((size_t)bhl << 8) + c0) * 256;
  const ushort* Bb = Vt + ((size_t)bhl << 18) + (size_t)n0 * 256;
  const int wr = w >> 1, wc = w & 1;
  f32x4 acc[4][4];
  #pragma unroll
  for (int mi = 0; mi < 4; ++mi)
    #pragma unroll
    for (int ni = 0; ni < 4; ++ni) {
      f32x4 z = {0.f, 0.f, 0.f, 0.f};
      acc[mi][ni] = z;
    }
  for (int kc = 0; kc < 256; kc += 32) {
    __syncthreads();
    #pragma unroll
    for (int q = 0; q < 2; ++q) {
      int idx = w * 128 + q * 64 + lane;
      int row = idx >> 2, seg = idx & 3;
      const ushort* srcA = Ab + (size_t)row * 256 + kc + seg * 8;
      const ushort* srcB = Bb + (size_t)row * 256 + kc + seg * 8;
      char* dstA = (char*)&As[0][0] + w * 2048 + q * 1024;
      char* dstB = (char*)&Bs[0][0] + w * 2048 + q * 1024;
      __builtin_amdgcn_global_load_lds(
          (const __attribute__((address_space(1))) unsigned*)srcA,
          (__attribute__((address_space(3))) unsigned*)dstA, 16, 0, 0);
      __builtin_amdgcn_global_load_lds(
          (const __attribute__((address_space(1))) unsigned*)srcB,
          (__attribute__((address_space(3))) unsigned*)dstB, 16, 0, 0);
    }
    __syncthreads();
    bf16x8 af[4], bfv[4];
    #pragma unroll
    for (int mi = 0; mi < 4; ++mi)
      af[mi] = *(const bf16x8*)&As[wr * 64 + mi * 16 + (lane & 15)][(lane >> 4) * 8];
    #pragma unroll
    for (int ni = 0; ni < 4; ++ni)
      bfv[ni] = *(const bf16x8*)&Bs[wc * 64 + ni * 16 + (lane & 15)][(lane >> 4) * 8];
    #pragma unroll
    for (int mi = 0; mi < 4; ++mi)
      #pragma unroll
      for (int ni = 0; ni < 4; ++ni)
        acc[mi][ni] = __builtin_amdgcn_mfma_f32_16x16x32_bf16(
            af[mi], bfv[ni], acc[mi][ni], 0, 0, 0);
  }
  const float gm = gamma[0];
  const int col = lane & 15, q = lane >> 4;
  #pragma unroll
  for (int mi = 0; mi < 4; ++mi) {
    const int gloc = wr * 8 + mi * 2 + (q >> 1);
    const int gp = gp_base + gloc;
    const float btv = bt_s[gloc];
    #pragma unroll
    for (int ni = 0; ni < 4; ++ni) {
      float pa[4] = {0.f, 0.f, 0.f, 0.f};
      #pragma unroll
      for (int r = 0; r < 4; ++r) {
        const int i2 = (q & 1) * 4 + r;
        const float a = acc[mi][ni][r];
        pa[0] += a * wt_s[gloc][i2 * 4 + 0];
        pa[1] += a * wt_s[gloc][i2 * 4 + 1];
        pa[2] += a * wt_s[gloc][i2 * 4 + 2];
        pa[3] += a * wt_s[gloc][i2 * 4 + 3];
      }
      float v0 = pa[0] + __shfl_xor(pa[0], 16, 64);
      float v1 = pa[1] + __shfl_xor(pa[1], 16, 64);
      float v2 = pa[2] + __shfl_xor(pa[2], 16, 64);
      float v3 = pa[3] + __shfl_xor(pa[3], 16, 64);
      const int lloc = wc * 64 + ni * 16 + col;
      const int l = n0 + lloc;
      const int p = l >> 5, j = l & 31;
      const int y = 2 * p + (q & 1);
      const float va = (q & 1) ? v2 : v0;
      const float vb = (q & 1) ? v3 : v1;
      const float* xc = x + (((size_t)b * 256 + gp) << 12) + (y << 6) + 2 * j;
      const int lp = (lloc << 2) + (q & 1) * 2;
      Ot[lp][gloc]     = f2bf(xc[0] + gm * (va + btv));
      Ot[lp + 1][gloc] = f2bf(xc[1] + gm * (vb + btv));
    }
  }
  __syncthreads();
  #pragma unroll
  for (int pp2 = 0; pp2 < 2; ++pp2) {
    const int pixl = tid * 2 + pp2;
    const int lloc = pixl >> 2;
    const int l = n0 + lloc;
    const int p = l >> 5, j = l & 31;
    const int yy = 2 * p + ((pixl >> 1) & 1) + 1;
    const int xx = 2 * j + (pixl & 1) + 1;
    const uint4* src = (const uint4*)&Ot[pixl][0];
    uint4* dst = (uint4*)(fused + ((size_t)b * 4356 + yy * 66 + xx) * 512 + 256 + gp_base);
    dst[0] = src[0];
    dst[1] = src[1];
  }
}

extern "C" void kernel_launch(void* const* d_in, const int* in_sizes, int n_in,
                              void* d_out, int out_size, void* d_ws, size_t ws_size,
                              hipStream_t stream)
{
  (void)in_sizes; (void)n_in; (void)out_size; (void)ws_size;
  const float* qkv_pos   = (const float*)d_in[0];
  const float* qkv_cha   = (const float*)d_in[1];
  const float* Wq_pos    = (const float*)d_in[2];
  const float* bq_pos    = (const float*)d_in[3];
  const float* Wk_pos    = (const float*)d_in[4];
  const float* bk_pos    = (const float*)d_in[5];
  const float* Wv_pos    = (const float*)d_in[6];
  const float* bv_pos    = (const float*)d_in[7];
  const float* Wo_pos    = (const float*)d_in[8];
  const float* bo_pos    = (const float*)d_in[9];
  const float* gamma_pos = (const float*)d_in[10];
  const float* Wq_cha    = (const float*)d_in[11];
  const float* bq_cha    = (const float*)d_in[12];
  const float* Wk_cha    = (const float*)d_in[13];
  const float* bk_cha    = (const float*)d_in[14];
  const float* Wv_cha    = (const float*)d_in[15];
  const float* bv_cha    = (const float*)d_in[16];
  const float* Wt_cha    = (const float*)d_in[17];
  const float* bt_cha    = (const float*)d_in[18];
  const float* gamma_cha = (const float*)d_in[19];
  const float* Wf        = (const float*)d_in[20];
  const float* bf        = (const float*)d_in[21];
  float* out = (float*)d_out;

  float* ws = (float*)d_ws;
  ushort* Wpf9    = (ushort*)ws;
  ushort* Wpo9    = (ushort*)(ws + 589824);
  // POS scratch
  ushort* Qb      = (ushort*)(ws + 884736);    // [64][1024][32] bf16
  ushort* Kb      = (ushort*)(ws + 1933312);   // [64][1024][32] bf16
  ushort* Vtb     = (ushort*)(ws + 2981888);   // [64][32][1024] bf16
  ushort* op_pad  = (ushort*)(ws + 4030464);   // 2367488 ushorts
  float*  op_conv = ws + 5214208;              // NHWC fp32 [8][1024][256]
  // CHA scratch (aliases POS region after it is consumed)
  ushort* qcb     = (ushort*)(ws + 884736);
  ushort* kcb     = (ushort*)(ws + 5079040);
  ushort* vcT     = (ushort*)(ws + 9273344);
  float*  attn_c  = ws + 13467648;
  ushort* Pb      = (ushort*)(ws + 15564800);
  ushort* fusedb  = (ushort*)(ws + 16613376);  // NHWC padded [8][66*66][512]

  // zero padded buffers (conv borders) and Qb (hd pad lanes 8..31 must be 0)
  hipMemsetAsync(op_pad, 0, (size_t)2367488 * 2, stream);
  hipMemsetAsync(fusedb, 0, (size_t)17842176 * 2, stream);
  hipMemsetAsync(Qb, 0, (size_t)2097152 * 2, stream);
  // weight pre-pack to [t][oc][c] bf16
  k_prepack9<512><<<dim3(4608), 256, 0, stream>>>(Wf, Wpf9);
  k_prepack9<256><<<dim3(2304), 256, 0, stream>>>(Wo_pos, Wpo9);
  // POS branch
  k_pos_qkv<<<dim3(6, 16, 8), 256, 0, stream>>>(qkv_pos, Wq_pos, bq_pos,
      Wk_pos, bk_pos, Wv_pos, bv_pos, Qb, Kb, Vtb);
  k_pos_flash<<<dim3(8, 8, 8), 256, 0, stream>>>(Qb, Kb, Vtb, op_pad);
  k_conv9_mfma<256, 32, 34, 1><<<dim3(8, 2, 8), 256, 0, stream>>>(
      op_pad, Wpo9, bo_pos, op_conv);
  k_upsample_nhwc<<<dim3(8192), 256, 0, stream>>>(qkv_pos, op_conv, gamma_pos, fusedb);
  // CHA branch, two half-batches
  for (int half = 0; half < 2; ++half) {
    const float* xh = qkv_cha + (size_t)half * 4 * 256 * 4096;
    k_cha_proj<<<dim3(1024), 256, 0, stream>>>(xh, Wq_cha, bq_cha,
        Wk_cha, bk_cha, Wv_cha, bv_cha, qcb, kcb, vcT);
    k_cha_scores_mfma<<<dim3(2, 2, 32), 256, 0, stream>>>(qcb, kcb, attn_c);
    k_softmax_p<<<dim3(2048), 256, 0, stream>>>(attn_c, Pb);
    k_cha_pv<<<dim3(8, 2, 32), 256, 0, stream>>>(Pb, vcT, qkv_cha,
        Wt_cha, bt_cha, gamma_cha, fusedb, half * 4);
  }
  // fusion conv (bf16 MFMA over padded NHWC)
  k_conv9_mfma<512, 64, 66, 0><<<dim3(32, 2, 8), 256, 0, stream>>>(
      fusedb, Wpf9, bf, out);
}

// Round 6
// 573.953 us; speedup vs baseline: 4.9366x; 1.2730x over previous
//
#include <hip/hip_runtime.h>
#include <math.h>

// Shapes: B=8, C=256, H=W=64, HQ=WQ=32, L=1024, NH=8, hd=8, dv=32
//
// Workspace (float units):
//   Wpf9 bf16[9][256][512] @ 0        (589824 f)
//   Wpo9 bf16[9][256][256] @ 589824   (294912 f)
//   region2 @ 884736 (POS scratch, later aliased by CHA scratch):
//     POS: Qb bf16[64][1024][32] @884736  (1048576 f, hd pad zeroed)
//          Kb bf16[64][1024][32] @1933312 (1048576 f)
//          Vtb bf16[64][32][1024] @2981888 (1048576 f)
//          op_pad bf16[8][34*34][256] @4030464 (1183744 f)
//          op_conv f32 NHWC [8][1024][256] @5214208 (2097152 f)
//          Ap bf16[8][1024][1024] @7311360 (4194304 f)  -- patchified x
//     CHA: qcb bf16 @884736 | kcb @5079040 | vcT @9273344 (4194304 f each)
//          attn_c f32 @13467648 (2097152) | P bf16 @15564800 (1048576 f)
//   fused_pad bf16[8][66*66][512] @ 16613376 (8921088 f)
//   Wqkv_p bf16[384][1024] @ 25534464 (196608 f)

typedef __attribute__((ext_vector_type(8))) short bf16x8;
typedef __attribute__((ext_vector_type(4))) float f32x4;

__device__ __forceinline__ ushort f2bf(float f) {
  union { float f; unsigned u; } v; v.f = f;
  unsigned r = (v.u + 0x7FFFu + ((v.u >> 16) & 1u)) >> 16;
  return (ushort)r;
}

// -------- weight pre-pack: W[oc][cin][3][3] fp32 -> [t][oc][cin] bf16 -------
template <int CIN>
__global__ __launch_bounds__(256) void k_prepack9(
    const float* __restrict__ W, ushort* __restrict__ out)
{
  const int i = blockIdx.x * 256 + threadIdx.x;   // over 9*256*CIN
  const int t = i / (256 * CIN);
  const int r = i - t * (256 * CIN);
  const int oc = r / CIN;
  const int c = r - oc * CIN;
  out[i] = f2bf(W[((size_t)oc * CIN + c) * 9 + t]);
}

// -------- concat Wq/Wk/Wv -> bf16 [384][1024] -------------------------------
__global__ __launch_bounds__(256) void k_cast_wqkv(
    const float* __restrict__ Wq, const float* __restrict__ Wk,
    const float* __restrict__ Wv, ushort* __restrict__ out)
{
  const int i = blockIdx.x * 256 + threadIdx.x;   // over 384*1024
  const int o = i >> 10, k = i & 1023;
  float v;
  if (o < 64)       v = Wq[(size_t)o * 1024 + k];
  else if (o < 128) v = Wk[(size_t)(o - 64) * 1024 + k];
  else              v = Wv[(size_t)(o - 128) * 1024 + k];
  out[i] = f2bf(v);
}

// -------- patchify x (2x2 stride-2 im2col) -> bf16 Ap[b][l][1024] -----------
__global__ __launch_bounds__(256) void k_pack_pos(
    const float* __restrict__ x, ushort* __restrict__ Ap)
{
  const int t = blockIdx.x * 256 + threadIdx.x;   // 524288 threads
  const int j4 = t & 7;          // group of 4 output cols
  const int i  = (t >> 3) & 31;  // output row
  const int c  = (t >> 8) & 255;
  const int b  = t >> 16;
  const float* xb = x + (((size_t)b * 256 + c) << 12) + (2 * i) * 64 + 8 * j4;
  union { float4 v[2]; float f[8]; } r0, r1;
  r0.v[0] = *(const float4*)(xb);
  r0.v[1] = *(const float4*)(xb + 4);
  r1.v[0] = *(const float4*)(xb + 64);
  r1.v[1] = *(const float4*)(xb + 68);
  #pragma unroll
  for (int jj = 0; jj < 4; ++jj) {
    const int l = i * 32 + j4 * 4 + jj;
    union { ushort u[4]; uint2 d; } pk;
    pk.u[0] = f2bf(r0.f[2 * jj]);
    pk.u[1] = f2bf(r0.f[2 * jj + 1]);
    pk.u[2] = f2bf(r1.f[2 * jj]);
    pk.u[3] = f2bf(r1.f[2 * jj + 1]);
    *(uint2*)(Ap + ((((size_t)b << 10) + l) << 10) + c * 4) = pk.d;
  }
}

// ---- P1: POS q/k/v projection as bf16 MFMA GEMM [384x1024]x[1024xL] --------
__global__ __launch_bounds__(256) void k_pos_qkv_mfma(
    const ushort* __restrict__ Ap, const ushort* __restrict__ Wqkv,
    const float* __restrict__ bq, const float* __restrict__ bk,
    const float* __restrict__ bv,
    ushort* __restrict__ Qb, ushort* __restrict__ Kb, ushort* __restrict__ Vtb)
{
  const int n0 = blockIdx.x * 128, oc0 = blockIdx.y * 128, b = blockIdx.z;
  const int tid = threadIdx.x, lane = tid & 63, w = tid >> 6;
  __shared__ ushort As[128][32], Bs[128][32];
  const ushort* Abw = Wqkv + (size_t)oc0 * 1024;
  const ushort* Bb  = Ap + (((size_t)b << 10) + n0) * 1024;
  const int wr = w >> 1, wc = w & 1;
  f32x4 acc[4][4];
  #pragma unroll
  for (int mi = 0; mi < 4; ++mi)
    #pragma unroll
    for (int ni = 0; ni < 4; ++ni) {
      f32x4 z = {0.f, 0.f, 0.f, 0.f};
      acc[mi][ni] = z;
    }
  for (int kc = 0; kc < 1024; kc += 32) {
    __syncthreads();
    #pragma unroll
    for (int q = 0; q < 2; ++q) {
      int idx = w * 128 + q * 64 + lane;
      int row = idx >> 2, seg = idx & 3;
      const ushort* srcA = Abw + (size_t)row * 1024 + kc + seg * 8;
      const ushort* srcB = Bb + (size_t)row * 1024 + kc + seg * 8;
      char* dstA = (char*)&As[0][0] + w * 2048 + q * 1024;
      char* dstB = (char*)&Bs[0][0] + w * 2048 + q * 1024;
      __builtin_amdgcn_global_load_lds(
          (const __attribute__((address_space(1))) unsigned*)srcA,
          (__attribute__((address_space(3))) unsigned*)dstA, 16, 0, 0);
      __builtin_amdgcn_global_load_lds(
          (const __attribute__((address_space(1))) unsigned*)srcB,
          (__attribute__((address_space(3))) unsigned*)dstB, 16, 0, 0);
    }
    __syncthreads();
    bf16x8 af[4], bfv[4];
    #pragma unroll
    for (int mi = 0; mi < 4; ++mi)
      af[mi] = *(const bf16x8*)&As[wr * 64 + mi * 16 + (lane & 15)][(lane >> 4) * 8];
    #pragma unroll
    for (int ni = 0; ni < 4; ++ni)
      bfv[ni] = *(const bf16x8*)&Bs[wc * 64 + ni * 16 + (lane & 15)][(lane >> 4) * 8];
    #pragma unroll
    for (int mi = 0; mi < 4; ++mi)
      #pragma unroll
      for (int ni = 0; ni < 4; ++ni)
        acc[mi][ni] = __builtin_amdgcn_mfma_f32_16x16x32_bf16(
            af[mi], bfv[ni], acc[mi][ni], 0, 0, 0);
  }
  // epilogue: scatter into flash layouts (Q scaled, bias added)
  #pragma unroll
  for (int mi = 0; mi < 4; ++mi) {
    const int oc = oc0 + wr * 64 + mi * 16 + (lane >> 4) * 4;  // mult of 4
    if (oc >= 384) continue;
    if (oc < 64) {
      const int hh = oc >> 3, e = oc & 7;
      float4 bb = *(const float4*)(bq + oc);
      #pragma unroll
      for (int ni = 0; ni < 4; ++ni) {
        const int l = n0 + wc * 64 + ni * 16 + (lane & 15);
        union { ushort u[4]; uint2 d; } pk;
        pk.u[0] = f2bf((acc[mi][ni][0] + bb.x) * 0.35355339059327373f);
        pk.u[1] = f2bf((acc[mi][ni][1] + bb.y) * 0.35355339059327373f);
        pk.u[2] = f2bf((acc[mi][ni][2] + bb.z) * 0.35355339059327373f);
        pk.u[3] = f2bf((acc[mi][ni][3] + bb.w) * 0.35355339059327373f);
        *(uint2*)(Qb + (((((size_t)b * 8 + hh) << 10) + l) << 5) + e) = pk.d;
      }
    } else if (oc < 128) {
      const int o2 = oc - 64, hh = o2 >> 3, e = o2 & 7;
      float4 bb = *(const float4*)(bk + o2);
      #pragma unroll
      for (int ni = 0; ni < 4; ++ni) {
        const int l = n0 + wc * 64 + ni * 16 + (lane & 15);
        union { ushort u[4]; uint2 d; } pk;
        pk.u[0] = f2bf(acc[mi][ni][0] + bb.x);
        pk.u[1] = f2bf(acc[mi][ni][1] + bb.y);
        pk.u[2] = f2bf(acc[mi][ni][2] + bb.z);
        pk.u[3] = f2bf(acc[mi][ni][3] + bb.w);
        *(uint2*)(Kb + (((((size_t)b * 8 + hh) << 10) + l) << 5) + e) = pk.d;
      }
    } else {
      const int o2 = oc - 128, hh = o2 >> 5, dd = o2 & 31;
      float4 bb = *(const float4*)(bv + o2);
      #pragma unroll
      for (int ni = 0; ni < 4; ++ni) {
        const int l = n0 + wc * 64 + ni * 16 + (lane & 15);
        ushort* vb = Vtb + ((((size_t)b * 8 + hh) * 32 + dd) << 10) + l;
        vb[0]      = f2bf(acc[mi][ni][0] + bb.x);
        vb[1024]   = f2bf(acc[mi][ni][1] + bb.y);
        vb[2048]   = f2bf(acc[mi][ni][2] + bb.z);
        vb[3072]   = f2bf(acc[mi][ni][3] + bb.w);
      }
    }
  }
}

// ---- P2: flash POS attention, bf16 MFMA, no barriers -----------------------
__global__ __launch_bounds__(256) void k_pos_flash(
    const ushort* __restrict__ Qb, const ushort* __restrict__ Kb,
    const ushort* __restrict__ Vtb, ushort* __restrict__ op_pad)
{
  const int qt = blockIdx.x, h = blockIdx.y, b = blockIdx.z;
  const int bh = b * 8 + h;
  const int tid = threadIdx.x, lane = tid & 63, wq = tid >> 6;
  const int c = lane & 15, g = lane >> 4;
  __shared__ __align__(16) ushort Ps[4][32][72];   // wave-private P tiles
  const int qbase = qt * 128 + wq * 32;
  bf16x8 qf[2];
  #pragma unroll
  for (int nt = 0; nt < 2; ++nt)
    qf[nt] = *(const bf16x8*)(Qb + (((size_t)bh << 10) + qbase + nt * 16 + c) * 32 + g * 8);
  f32x4 o[2][2];
  #pragma unroll
  for (int mt = 0; mt < 2; ++mt)
    #pragma unroll
    for (int nt = 0; nt < 2; ++nt) {
      f32x4 z = {0.f, 0.f, 0.f, 0.f};
      o[mt][nt] = z;
    }
  float m[2] = {-1e30f, -1e30f}, l[2] = {0.f, 0.f};
  const ushort* Kbh = Kb + ((size_t)bh << 15);
  const ushort* Vbh = Vtb + ((size_t)bh << 15);

  for (int kt = 0; kt < 16; ++kt) {
    const int kb0 = kt * 64;
    bf16x8 kf[4];
    #pragma unroll
    for (int mt = 0; mt < 4; ++mt)
      kf[mt] = *(const bf16x8*)(Kbh + (size_t)(kb0 + mt * 16 + c) * 32 + g * 8);
    f32x4 s[4][2];
    #pragma unroll
    for (int mt = 0; mt < 4; ++mt)
      #pragma unroll
      for (int nt = 0; nt < 2; ++nt) {
        f32x4 z = {0.f, 0.f, 0.f, 0.f};
        s[mt][nt] = __builtin_amdgcn_mfma_f32_16x16x32_bf16(kf[mt], qf[nt], z, 0, 0, 0);
      }
    #pragma unroll
    for (int nt = 0; nt < 2; ++nt) {
      float tmax = -1e30f;
      #pragma unroll
      for (int mt = 0; mt < 4; ++mt)
        #pragma unroll
        for (int r = 0; r < 4; ++r)
          tmax = fmaxf(tmax, s[mt][nt][r]);
      tmax = fmaxf(tmax, __shfl_xor(tmax, 16, 64));
      tmax = fmaxf(tmax, __shfl_xor(tmax, 32, 64));
      const float mn = fmaxf(m[nt], tmax);
      const float alpha = __expf(m[nt] - mn);
      m[nt] = mn;
      float rs = 0.f;
      #pragma unroll
      for (int mt = 0; mt < 4; ++mt) {
        union { ushort u[4]; uint2 d; } pk;
        #pragma unroll
        for (int r = 0; r < 4; ++r) {
          float p = __expf(s[mt][nt][r] - mn);
          rs += p;
          pk.u[r] = f2bf(p);
        }
        *(uint2*)&Ps[wq][nt * 16 + c][mt * 16 + g * 4] = pk.d;
      }
      rs += __shfl_xor(rs, 16, 64);
      rs += __shfl_xor(rs, 32, 64);
      l[nt] = l[nt] * alpha + rs;
      #pragma unroll
      for (int mt = 0; mt < 2; ++mt)
        #pragma unroll
        for (int r = 0; r < 4; ++r)
          o[mt][nt][r] *= alpha;
    }
    #pragma unroll
    for (int kc = 0; kc < 2; ++kc) {
      bf16x8 vf[2], pf[2];
      #pragma unroll
      for (int mt = 0; mt < 2; ++mt)
        vf[mt] = *(const bf16x8*)(Vbh + (size_t)(mt * 16 + c) * 1024 + kb0 + kc * 32 + g * 8);
      #pragma unroll
      for (int nt = 0; nt < 2; ++nt)
        pf[nt] = *(const bf16x8*)&Ps[wq][nt * 16 + c][kc * 32 + g * 8];
      #pragma unroll
      for (int mt = 0; mt < 2; ++mt)
        #pragma unroll
        for (int nt = 0; nt < 2; ++nt)
          o[mt][nt] = __builtin_amdgcn_mfma_f32_16x16x32_bf16(vf[mt], pf[nt], o[mt][nt], 0, 0, 0);
    }
  }
  #pragma unroll
  for (int nt = 0; nt < 2; ++nt) {
    const float linv = 1.f / l[nt];
    const int q = qbase + nt * 16 + c;
    const int y = q >> 5, x = q & 31;
    ushort* dst = op_pad + ((size_t)b * 1156 + (y + 1) * 34 + (x + 1)) * 256 + h * 32;
    #pragma unroll
    for (int mt = 0; mt < 2; ++mt) {
      union { ushort u[4]; uint2 d; } pk;
      #pragma unroll
      for (int r = 0; r < 4; ++r)
        pk.u[r] = f2bf(o[mt][nt][r] * linv);
      *(uint2*)(dst + mt * 16 + g * 4) = pk.d;
    }
  }
}

// ------ 3x3 conv as 9 shifted GEMMs over padded NHWC, bf16 MFMA -------------
template <int CIN, int S, int PW, int OUT_NHWC>
__global__ __launch_bounds__(256) void k_conv9_mfma(
    const ushort* __restrict__ in, const ushort* __restrict__ W9,
    const float* __restrict__ bias, float* __restrict__ out)
{
  const int n0 = blockIdx.x * 128, oc0 = blockIdx.y * 128, b = blockIdx.z;
  const int tid = threadIdx.x, lane = tid & 63, w = tid >> 6;
  __shared__ ushort As[128][32], Bs[128][32];
  const int wr = w >> 1, wc = w & 1;
  f32x4 acc[4][4];
  #pragma unroll
  for (int mi = 0; mi < 4; ++mi)
    #pragma unroll
    for (int ni = 0; ni < 4; ++ni) {
      f32x4 z = {0.f, 0.f, 0.f, 0.f};
      acc[mi][ni] = z;
    }
  int rowq[2], segq[2], basep[2];
  #pragma unroll
  for (int q = 0; q < 2; ++q) {
    int idx = w * 128 + q * 64 + lane;
    rowq[q] = idx >> 2;
    segq[q] = (idx & 3) * 8;
    int n = n0 + rowq[q];
    int y = n / S, x = n % S;
    basep[q] = y * PW + x;
  }
  const ushort* inb = in + (size_t)b * (PW * PW) * CIN;

  for (int t = 0; t < 9; ++t) {
    const int offp = (t / 3) * PW + (t % 3);
    const ushort* wt = W9 + (size_t)t * 256 * CIN;
    for (int kc = 0; kc < CIN; kc += 32) {
      __syncthreads();
      #pragma unroll
      for (int q = 0; q < 2; ++q) {
        const ushort* srcA = wt + (size_t)(oc0 + rowq[q]) * CIN + kc + segq[q];
        const ushort* srcB = inb + (size_t)(basep[q] + offp) * CIN + kc + segq[q];
        char* dstA = (char*)&As[0][0] + w * 2048 + q * 1024;
        char* dstB = (char*)&Bs[0][0] + w * 2048 + q * 1024;
        __builtin_amdgcn_global_load_lds(
            (const __attribute__((address_space(1))) unsigned*)srcA,
            (__attribute__((address_space(3))) unsigned*)dstA, 16, 0, 0);
        __builtin_amdgcn_global_load_lds(
            (const __attribute__((address_space(1))) unsigned*)srcB,
            (__attribute__((address_space(3))) unsigned*)dstB, 16, 0, 0);
      }
      __syncthreads();
      bf16x8 af[4], bfv[4];
      #pragma unroll
      for (int mi = 0; mi < 4; ++mi)
        af[mi] = *(const bf16x8*)&As[wr * 64 + mi * 16 + (lane & 15)][(lane >> 4) * 8];
      #pragma unroll
      for (int ni = 0; ni < 4; ++ni)
        bfv[ni] = *(const bf16x8*)&Bs[wc * 64 + ni * 16 + (lane & 15)][(lane >> 4) * 8];
      #pragma unroll
      for (int mi = 0; mi < 4; ++mi)
        #pragma unroll
        for (int ni = 0; ni < 4; ++ni)
          acc[mi][ni] = __builtin_amdgcn_mfma_f32_16x16x32_bf16(
              af[mi], bfv[ni], acc[mi][ni], 0, 0, 0);
    }
  }
  if (OUT_NHWC) {
    float* outb = out + (size_t)b * (S * S) * 256;
    #pragma unroll
    for (int mi = 0; mi < 4; ++mi) {
      const int oc = oc0 + wr * 64 + mi * 16 + (lane >> 4) * 4;
      float4 bb = *(const float4*)(bias + oc);
      #pragma unroll
      for (int ni = 0; ni < 4; ++ni) {
        const int n = n0 + wc * 64 + ni * 16 + (lane & 15);
        float4 v;
        v.x = acc[mi][ni][0] + bb.x;
        v.y = acc[mi][ni][1] + bb.y;
        v.z = acc[mi][ni][2] + bb.z;
        v.w = acc[mi][ni][3] + bb.w;
        *(float4*)(outb + (size_t)n * 256 + oc) = v;
      }
    }
  } else {
    float* outb = out + (size_t)b * 256 * (S * S);
    #pragma unroll
    for (int mi = 0; mi < 4; ++mi) {
      #pragma unroll
      for (int r = 0; r < 4; ++r) {
        int oc = oc0 + wr * 64 + mi * 16 + (lane >> 4) * 4 + r;
        float bb = bias[oc];
        #pragma unroll
        for (int ni = 0; ni < 4; ++ni) {
          int n = n0 + wc * 64 + ni * 16 + (lane & 15);
          outb[(size_t)oc * (S * S) + n] = acc[mi][ni][r] + bb;
        }
      }
    }
  }
}

// ---- P4: bilinear x2 upsample + residual -> fused_pad[.., ch 0:256] --------
__global__ __launch_bounds__(256) void k_upsample_nhwc(
    const float* __restrict__ xpos, const float* __restrict__ opc,
    const float* __restrict__ gamma, ushort* __restrict__ fused)
{
  const int t = blockIdx.x * 256 + threadIdx.x;  // 8*4096*64
  const int c = (t & 63) * 4;
  const int pix = (t >> 6) & 4095;
  const int b = t >> 18;
  const int y = pix >> 6, xx = pix & 63;
  const int my = y >> 1;
  const int y0 = (y & 1) ? my : my - 1;
  const float fy = (y & 1) ? 0.25f : 0.75f;
  const int mx = xx >> 1;
  const int x0 = (xx & 1) ? mx : mx - 1;
  const float fx = (xx & 1) ? 0.25f : 0.75f;
  const int y0c = max(y0, 0), y1c = min(y0 + 1, 31);
  const int x0c = max(x0, 0), x1c = min(x0 + 1, 31);
  const float* base = opc + (size_t)b * 1024 * 256 + c;
  float4 v00 = *(const float4*)(base + (size_t)(y0c * 32 + x0c) * 256);
  float4 v01 = *(const float4*)(base + (size_t)(y0c * 32 + x1c) * 256);
  float4 v10 = *(const float4*)(base + (size_t)(y1c * 32 + x0c) * 256);
  float4 v11 = *(const float4*)(base + (size_t)(y1c * 32 + x1c) * 256);
  const float w00 = (1.f - fy) * (1.f - fx), w01 = (1.f - fy) * fx;
  const float w10 = fy * (1.f - fx), w11 = fy * fx;
  const float g = gamma[0];
  const float* xr = xpos + ((size_t)b * 256 + c) * 4096 + pix;
  union { ushort u[4]; uint2 q; } o;
  o.u[0] = f2bf(xr[0]          + g * (w00 * v00.x + w01 * v01.x + w10 * v10.x + w11 * v11.x));
  o.u[1] = f2bf(xr[4096]       + g * (w00 * v00.y + w01 * v01.y + w10 * v10.y + w11 * v11.y));
  o.u[2] = f2bf(xr[2 * 4096]   + g * (w00 * v00.z + w01 * v01.z + w10 * v10.z + w11 * v11.z));
  o.u[3] = f2bf(xr[3 * 4096]   + g * (w00 * v00.w + w01 * v01.w + w10 * v10.w + w11 * v11.w));
  *(uint2*)(fused + ((size_t)b * 4356 + (y + 1) * 66 + (xx + 1)) * 512 + c) = o.q;
}

// ------- C0: CHA q/k/v grouped 2x2 projections -> bf16 (half-batch) ---------
__global__ __launch_bounds__(256) void k_cha_proj(
    const float* __restrict__ x,
    const float* __restrict__ Wq, const float* __restrict__ bq,
    const float* __restrict__ Wk, const float* __restrict__ bk,
    const float* __restrict__ Wv, const float* __restrict__ bv,
    ushort* __restrict__ Qc, ushort* __restrict__ Kc, ushort* __restrict__ Vt)
{
  const int t = blockIdx.x * 256 + threadIdx.x;
  const int bl = t >> 16;
  const int g  = (t >> 8) & 255;
  const int lq = t & 255;
  const int i = lq >> 3, j4 = (lq & 7) << 2;
  const float* xb = x + (((size_t)bl * 256 + g) << 12) + (2 * i) * 64 + 2 * j4;
  union { float4 v[2]; float f[8]; } xr0, xr1;
  xr0.v[0] = *(const float4*)(xb);
  xr0.v[1] = *(const float4*)(xb + 4);
  xr1.v[0] = *(const float4*)(xb + 64);
  xr1.v[1] = *(const float4*)(xb + 68);
  const int bhl = bl * 8 + (g >> 5);
  const int c2b = (g & 31) * 8;
  const int l0 = i * 32 + j4;
  #pragma unroll
  for (int h = 0; h < 8; ++h) {
    float4 w4 = *(const float4*)(Wq + g * 32 + h * 4);
    float bb = bq[g * 8 + h];
    union { ushort u[4]; uint2 q; } o;
    #pragma unroll
    for (int jj = 0; jj < 4; ++jj) {
      float v = xr0.f[2 * jj] * w4.x + xr0.f[2 * jj + 1] * w4.y
              + xr1.f[2 * jj] * w4.z + xr1.f[2 * jj + 1] * w4.w + bb;
      o.u[jj] = f2bf(v * 0.03125f);
    }
    *(uint2*)(Qc + (((size_t)bhl * 256 + c2b + h) << 10) + l0) = o.q;
  }
  #pragma unroll
  for (int h = 0; h < 8; ++h) {
    float4 w4 = *(const float4*)(Wk + g * 32 + h * 4);
    float bb = bk[g * 8 + h];
    union { ushort u[4]; uint2 q; } o;
    #pragma unroll
    for (int jj = 0; jj < 4; ++jj) {
      float v = xr0.f[2 * jj] * w4.x + xr0.f[2 * jj + 1] * w4.y
              + xr1.f[2 * jj] * w4.z + xr1.f[2 * jj + 1] * w4.w + bb;
      o.u[jj] = f2bf(v);
    }
    *(uint2*)(Kc + (((size_t)bhl * 256 + c2b + h) << 10) + l0) = o.q;
  }
  ushort vo[4][8];
  #pragma unroll
  for (int h = 0; h < 8; ++h) {
    float4 w4 = *(const float4*)(Wv + g * 32 + h * 4);
    float bb = bv[g * 8 + h];
    #pragma unroll
    for (int jj = 0; jj < 4; ++jj) {
      float v = xr0.f[2 * jj] * w4.x + xr0.f[2 * jj + 1] * w4.y
              + xr1.f[2 * jj] * w4.z + xr1.f[2 * jj + 1] * w4.w + bb;
      vo[jj][h] = f2bf(v);
    }
  }
  #pragma unroll
  for (int jj = 0; jj < 4; ++jj)
    *(uint4*)(Vt + ((size_t)bhl << 18) + (size_t)(l0 + jj) * 256 + c2b) =
        *(uint4*)&vo[jj][0];
}

// ------- C1: scores = qc @ kc^T, bf16 MFMA, K=1024 (half-batch) -------------
__global__ __launch_bounds__(256) void k_cha_scores_mfma(
    const ushort* __restrict__ Qc, const ushort* __restrict__ Kc,
    float* __restrict__ S)
{
  const int c0 = blockIdx.x * 128, d0 = blockIdx.y * 128, bhl = blockIdx.z;
  const int tid = threadIdx.x, lane = tid & 63, w = tid >> 6;
  __shared__ ushort As[128][32], Bs[128][32];
  const ushort* Ab = Qc + ((size_t)bhl * 256 + c0) * 1024;
  const ushort* Bb = Kc + ((size_t)bhl * 256 + d0) * 1024;
  const int wr = w >> 1, wc = w & 1;
  f32x4 acc[4][4];
  #pragma unroll
  for (int mi = 0; mi < 4; ++mi)
    #pragma unroll
    for (int ni = 0; ni < 4; ++ni) {
      f32x4 z = {0.f, 0.f, 0.f, 0.f};
      acc[mi][ni] = z;
    }
  for (int kc = 0; kc < 1024; kc += 32) {
    __syncthreads();
    #pragma unroll
    for (int q = 0; q < 2; ++q) {
      int idx = w * 128 + q * 64 + lane;
      int row = idx >> 2, seg = idx & 3;
      const ushort* srcA = Ab + (size_t)row * 1024 + kc + seg * 8;
      const ushort* srcB = Bb + (size_t)row * 1024 + kc + seg * 8;
      char* dstA = (char*)&As[0][0] + w * 2048 + q * 1024;
      char* dstB = (char*)&Bs[0][0] + w * 2048 + q * 1024;
      __builtin_amdgcn_global_load_lds(
          (const __attribute__((address_space(1))) unsigned*)srcA,
          (__attribute__((address_space(3))) unsigned*)dstA, 16, 0, 0);
      __builtin_amdgcn_global_load_lds(
          (const __attribute__((address_space(1))) unsigned*)srcB,
          (__attribute__((address_space(3))) unsigned*)dstB, 16, 0, 0);
    }
    __syncthreads();
    bf16x8 af[4], bfv[4];
    #pragma unroll
    for (int mi = 0; mi < 4; ++mi)
      af[mi] = *(const bf16x8*)&As[wr * 64 + mi * 16 + (lane & 15)][(lane >> 4) * 8];
    #pragma unroll
    for (int ni = 0; ni < 4; ++ni)
      bfv[ni] = *(const bf16x8*)&Bs[wc * 64 + ni * 16 + (lane & 15)][(lane >> 4) * 8];
    #pragma unroll
    for (int mi = 0; mi < 4; ++mi)
      #pragma unroll
      for (int ni = 0; ni < 4; ++ni)
        acc[mi][ni] = __builtin_amdgcn_mfma_f32_16x16x32_bf16(
            af[mi], bfv[ni], acc[mi][ni], 0, 0, 0);
  }
  float* Sb = S + ((size_t)bhl << 16);
  #pragma unroll
  for (int mi = 0; mi < 4; ++mi)
    #pragma unroll
    for (int r = 0; r < 4; ++r) {
      int c = c0 + wr * 64 + mi * 16 + (lane >> 4) * 4 + r;
      #pragma unroll
      for (int ni = 0; ni < 4; ++ni) {
        int d = d0 + wc * 64 + ni * 16 + (lane & 15);
        Sb[(size_t)c * 256 + d] = acc[mi][ni][r];
      }
    }
}

// ------- C2: row softmax over 256 -> bf16 P ---------------------------------
__global__ __launch_bounds__(256) void k_softmax_p(
    const float* __restrict__ S, ushort* __restrict__ P)
{
  const int row = blockIdx.x * 4 + (threadIdx.x >> 6);
  const int lane = threadIdx.x & 63;
  const float* r = S + (size_t)row * 256;
  float4 v = *(const float4*)(r + lane * 4);
  float m = fmaxf(fmaxf(v.x, v.y), fmaxf(v.z, v.w));
  #pragma unroll
  for (int off = 32; off; off >>= 1) m = fmaxf(m, __shfl_xor(m, off, 64));
  v.x = __expf(v.x - m); v.y = __expf(v.y - m);
  v.z = __expf(v.z - m); v.w = __expf(v.w - m);
  float s = v.x + v.y + v.z + v.w;
  #pragma unroll
  for (int off = 32; off; off >>= 1) s += __shfl_xor(s, off, 64);
  const float inv = 1.f / s;
  union { ushort u[4]; uint2 q; } o;
  o.u[0] = f2bf(v.x * inv); o.u[1] = f2bf(v.y * inv);
  o.u[2] = f2bf(v.z * inv); o.u[3] = f2bf(v.w * inv);
  *(uint2*)(P + (size_t)row * 256 + lane * 4) = o.q;
}

// -- C3: oc = P @ vcT (MFMA) + grouped ConvT + residual -> fused_pad NHWC ----
__global__ __launch_bounds__(256) void k_cha_pv(
    const ushort* __restrict__ P, const ushort* __restrict__ Vt,
    const float* __restrict__ x,
    const float* __restrict__ Wt, const float* __restrict__ bt,
    const float* __restrict__ gamma, ushort* __restrict__ fused, int bbase)
{
  const int n0 = blockIdx.x * 128, c0 = blockIdx.y * 128, bhl = blockIdx.z;
  const int b = bbase + (bhl >> 3), h = bhl & 7;
  const int tid = threadIdx.x, lane = tid & 63, w = tid >> 6;
  __shared__ ushort As[128][32], Bs[128][32];
  __shared__ ushort Ot[512][16];
  __shared__ float wt_s[16][32];
  __shared__ float bt_s[16];
  const int gp_base = h * 32 + (c0 >> 3);
  {
    int e = tid;
    wt_s[e >> 5][e & 31] = Wt[(size_t)gp_base * 32 + e];
    e += 256;
    wt_s[e >> 5][e & 31] = Wt[(size_t)gp_base * 32 + e];
    if (tid < 16) bt_s[tid] = bt[gp_base + tid];
  }
  const ushort* Ab = P + (((size_t)bhl << 8) + c0) * 256;
  const ushort* Bb = Vt + ((size_t)bhl << 18) + (size_t)n0 * 256;
  const int wr = w >> 1, wc = w & 1;
  f32x4 acc[4][4];
  #pragma unroll
  for (int mi = 0; mi < 4; ++mi)
    #pragma unroll
    for (int ni = 0; ni < 4; ++ni) {
      f32x4 z = {0.f, 0.f, 0.f, 0.f};
      acc[mi][ni] = z;
    }
  for (int kc = 0; kc < 256; kc += 32) {
    __syncthreads();
    #pragma unroll
    for (int q = 0; q < 2; ++q) {
      int idx = w * 128 + q * 64 + lane;
      int row = idx >> 2, seg = idx & 3;
      const ushort* srcA = Ab + (size_t)row * 256 + kc + seg * 8;
      const ushort* srcB = Bb + (size_t)row * 256 + kc + seg * 8;
      char* dstA = (char*)&As[0][0] + w * 2048 + q * 1024;
      char* dstB = (char*)&Bs[0][0] + w * 2048 + q * 1024;
      __builtin_amdgcn_global_load_lds(
          (const __attribute__((address_space(1))) unsigned*)srcA,
          (__attribute__((address_space(3))) unsigned*)dstA, 16, 0, 0);
      __builtin_amdgcn_global_load_lds(
          (const __attribute__((address_space(1))) unsigned*)srcB,
          (__attribute__((address_space(3))) unsigned*)dstB, 16, 0, 0);
    }
    __syncthreads();
    bf16x8 af[4], bfv[4];
    #pragma unroll
    for (int mi = 0; mi < 4; ++mi)
      af[mi] = *(const bf16x8*)&As[wr * 64 + mi * 16 + (lane & 15)][(lane >> 4) * 8];
    #pragma unroll
    for (int ni = 0; ni < 4; ++ni)
      bfv[ni] = *(const bf16x8*)&Bs[wc * 64 + ni * 16 + (lane & 15)][(lane >> 4) * 8];
    #pragma unroll
    for (int mi = 0; mi < 4; ++mi)
      #pragma unroll
      for (int ni = 0; ni < 4; ++ni)
        acc[mi][ni] = __builtin_amdgcn_mfma_f32_16x16x32_bf16(
            af[mi], bfv[ni], acc[mi][ni], 0, 0, 0);
  }
  const float gm = gamma[0];
  const int col = lane & 15, q = lane >> 4;
  #pragma unroll
  for (int mi = 0; mi < 4; ++mi) {
    const int gloc = wr * 8 + mi * 2 + (q >> 1);
    const int gp = gp_base + gloc;
    const float btv = bt_s[gloc];
    #pragma unroll
    for (int ni = 0; ni < 4; ++ni) {
      float pa[4] = {0.f, 0.f, 0.f, 0.f};
      #pragma unroll
      for (int r = 0; r < 4; ++r) {
        const int i2 = (q & 1) * 4 + r;
        const float a = acc[mi][ni][r];
        pa[0] += a * wt_s[gloc][i2 * 4 + 0];
        pa[1] += a * wt_s[gloc][i2 * 4 + 1];
        pa[2] += a * wt_s[gloc][i2 * 4 + 2];
        pa[3] += a * wt_s[gloc][i2 * 4 + 3];
      }
      float v0 = pa[0] + __shfl_xor(pa[0], 16, 64);
      float v1 = pa[1] + __shfl_xor(pa[1], 16, 64);
      float v2 = pa[2] + __shfl_xor(pa[2], 16, 64);
      float v3 = pa[3] + __shfl_xor(pa[3], 16, 64);
      const int lloc = wc * 64 + ni * 16 + col;
      const int l = n0 + lloc;
      const int p = l >> 5, j = l & 31;
      const int y = 2 * p + (q & 1);
      const float va = (q & 1) ? v2 : v0;
      const float vb = (q & 1) ? v3 : v1;
      const float* xc = x + (((size_t)b * 256 + gp) << 12) + (y << 6) + 2 * j;
      const int lp = (lloc << 2) + (q & 1) * 2;
      Ot[lp][gloc]     = f2bf(xc[0] + gm * (va + btv));
      Ot[lp + 1][gloc] = f2bf(xc[1] + gm * (vb + btv));
    }
  }
  __syncthreads();
  #pragma unroll
  for (int pp2 = 0; pp2 < 2; ++pp2) {
    const int pixl = tid * 2 + pp2;
    const int lloc = pixl >> 2;
    const int l = n0 + lloc;
    const int p = l >> 5, j = l & 31;
    const int yy = 2 * p + ((pixl >> 1) & 1) + 1;
    const int xx = 2 * j + (pixl & 1) + 1;
    const uint4* src = (const uint4*)&Ot[pixl][0];
    uint4* dst = (uint4*)(fused + ((size_t)b * 4356 + yy * 66 + xx) * 512 + 256 + gp_base);
    dst[0] = src[0];
    dst[1] = src[1];
  }
}

extern "C" void kernel_launch(void* const* d_in, const int* in_sizes, int n_in,
                              void* d_out, int out_size, void* d_ws, size_t ws_size,
                              hipStream_t stream)
{
  (void)in_sizes; (void)n_in; (void)out_size; (void)ws_size;
  const float* qkv_pos   = (const float*)d_in[0];
  const float* qkv_cha   = (const float*)d_in[1];
  const float* Wq_pos    = (const float*)d_in[2];
  const float* bq_pos    = (const float*)d_in[3];
  const float* Wk_pos    = (const float*)d_in[4];
  const float* bk_pos    = (const float*)d_in[5];
  const float* Wv_pos    = (const float*)d_in[6];
  const float* bv_pos    = (const float*)d_in[7];
  const float* Wo_pos    = (const float*)d_in[8];
  const float* bo_pos    = (const float*)d_in[9];
  const float* gamma_pos = (const float*)d_in[10];
  const float* Wq_cha    = (const float*)d_in[11];
  const float* bq_cha    = (const float*)d_in[12];
  const float* Wk_cha    = (const float*)d_in[13];
  const float* bk_cha    = (const float*)d_in[14];
  const float* Wv_cha    = (const float*)d_in[15];
  const float* bv_cha    = (const float*)d_in[16];
  const float* Wt_cha    = (const float*)d_in[17];
  const float* bt_cha    = (const float*)d_in[18];
  const float* gamma_cha = (const float*)d_in[19];
  const float* Wf        = (const float*)d_in[20];
  const float* bf        = (const float*)d_in[21];
  float* out = (float*)d_out;

  float* ws = (float*)d_ws;
  ushort* Wpf9    = (ushort*)ws;
  ushort* Wpo9    = (ushort*)(ws + 589824);
  // POS scratch
  ushort* Qb      = (ushort*)(ws + 884736);    // [64][1024][32] bf16
  ushort* Kb      = (ushort*)(ws + 1933312);   // [64][1024][32] bf16
  ushort* Vtb     = (ushort*)(ws + 2981888);   // [64][32][1024] bf16
  ushort* op_pad  = (ushort*)(ws + 4030464);   // 2367488 ushorts
  float*  op_conv = ws + 5214208;              // NHWC fp32 [8][1024][256]
  ushort* Ap      = (ushort*)(ws + 7311360);   // [8][1024][1024] bf16
  // CHA scratch (aliases POS region after it is consumed)
  ushort* qcb     = (ushort*)(ws + 884736);
  ushort* kcb     = (ushort*)(ws + 5079040);
  ushort* vcT     = (ushort*)(ws + 9273344);
  float*  attn_c  = ws + 13467648;
  ushort* Pb      = (ushort*)(ws + 15564800);
  ushort* fusedb  = (ushort*)(ws + 16613376);  // NHWC padded [8][66*66][512]
  ushort* Wqkvp   = (ushort*)(ws + 25534464);  // [384][1024] bf16

  // zero padded buffers (conv borders) and Qb (hd pad lanes 8..31 must be 0)
  hipMemsetAsync(op_pad, 0, (size_t)2367488 * 2, stream);
  hipMemsetAsync(fusedb, 0, (size_t)17842176 * 2, stream);
  hipMemsetAsync(Qb, 0, (size_t)2097152 * 2, stream);
  // weight pre-packs
  k_prepack9<512><<<dim3(4608), 256, 0, stream>>>(Wf, Wpf9);
  k_prepack9<256><<<dim3(2304), 256, 0, stream>>>(Wo_pos, Wpo9);
  k_cast_wqkv<<<dim3(1536), 256, 0, stream>>>(Wq_pos, Wk_pos, Wv_pos, Wqkvp);
  // POS branch
  k_pack_pos<<<dim3(2048), 256, 0, stream>>>(qkv_pos, Ap);
  k_pos_qkv_mfma<<<dim3(8, 3, 8), 256, 0, stream>>>(Ap, Wqkvp,
      bq_pos, bk_pos, bv_pos, Qb, Kb, Vtb);
  k_pos_flash<<<dim3(8, 8, 8), 256, 0, stream>>>(Qb, Kb, Vtb, op_pad);
  k_conv9_mfma<256, 32, 34, 1><<<dim3(8, 2, 8), 256, 0, stream>>>(
      op_pad, Wpo9, bo_pos, op_conv);
  k_upsample_nhwc<<<dim3(8192), 256, 0, stream>>>(qkv_pos, op_conv, gamma_pos, fusedb);
  // CHA branch, two half-batches
  for (int half = 0; half < 2; ++half) {
    const float* xh = qkv_cha + (size_t)half * 4 * 256 * 4096;
    k_cha_proj<<<dim3(1024), 256, 0, stream>>>(xh, Wq_cha, bq_cha,
        Wk_cha, bk_cha, Wv_cha, bv_cha, qcb, kcb, vcT);
    k_cha_scores_mfma<<<dim3(2, 2, 32), 256, 0, stream>>>(qcb, kcb, attn_c);
    k_softmax_p<<<dim3(2048), 256, 0, stream>>>(attn_c, Pb);
    k_cha_pv<<<dim3(8, 2, 32), 256, 0, stream>>>(Pb, vcT, qkv_cha,
        Wt_cha, bt_cha, gamma_cha, fusedb, half * 4);
  }
  // fusion conv (bf16 MFMA over padded NHWC)
  k_conv9_mfma<512, 64, 66, 0><<<dim3(32, 2, 8), 256, 0, stream>>>(
      fusedb, Wpf9, bf, out);
}